// Round 12
// baseline (8427.724 us; speedup 1.0000x reference)
//
#include <hip/hip_runtime.h>
#include <math.h>

#define BB 64      // batch
#define SS 512     // seq len
#define EE 128     // embed dim
#define HH 256     // hidden
#define NC 9       // classes
#define G4 1024    // 4*H gates (one direction)
#define TCLOG 7
#define TC 128     // time chunk
#define NCH (SS / TC)
#define NPAIR 32   // batch pairs
#define KL 18      // k4 chunks cached in LDS per block (of 64) = 144 KB

#define ALD(p)    __hip_atomic_load((p), __ATOMIC_RELAXED, __HIP_MEMORY_SCOPE_AGENT)
#define AST(p,v)  __hip_atomic_store((p), (v), __ATOMIC_RELAXED, __HIP_MEMORY_SCOPE_AGENT)
#define AADD(p,v) __hip_atomic_fetch_add((p), (v), __ATOMIC_RELAXED, __HIP_MEMORY_SCOPE_AGENT)

// ---------- activations ----------
__device__ __forceinline__ float sigf(float x) {
    return 1.0f / (1.0f + __expf(-x));
}
__device__ __forceinline__ float tanhfast(float x) {
    float a = fabsf(x);
    float e = __expf(-2.0f * a);
    float t = (1.0f - e) / (1.0f + e);
    return copysignf(t, x);
}
__device__ __forceinline__ float dot4(float4 w, float4 h, float a) {
    a = fmaf(w.x, h.x, a); a = fmaf(w.y, h.y, a);
    a = fmaf(w.z, h.z, a); a = fmaf(w.w, h.w, a);
    return a;
}

__global__ void zero_k(float* p, int n) {
    int i = blockIdx.x * 256 + threadIdx.x;
    if (i < n) p[i] = 0.f;
}

// ---------- transpose w_hh -> wT[dir][k4][j][4] ----------
__global__ void transpose_whh(const float* __restrict__ whh, float* __restrict__ wT) {
    int idx = blockIdx.x * 256 + threadIdx.x;
    if (idx >= 2 * 64 * 1024) return;
    int jj  = idx & 1023;
    int k4  = (idx >> 10) & 63;
    int dir = idx >> 16;
    float4 v = *(const float4*)(whh + ((long)(dir * 1024 + jj)) * 256 + (k4 << 2));
    *(float4*)(wT + (((long)(dir * 64 + k4)) * 1024 + jj) * 4) = v;
}

// ---------- tiled f32 GEMM (proven round-3) ----------
template <int KDIM, bool GATHER>
__global__ __launch_bounds__(256) void gemm_xg(
    const float* __restrict__ A, const int* __restrict__ tokens,
    const float* __restrict__ W, const float* __restrict__ bias,
    float* __restrict__ out, int t_base, int t_sign)
{
    __shared__ float As[16][68];
    __shared__ float Bs[16][68];
    const int tid = threadIdx.x;
    const int m0 = blockIdx.x * 64;
    const int n0 = blockIdx.y * 64;

    const int lr = tid >> 2;
    const int lk = (tid & 3) * 4;
    const int mload = m0 + lr;
    const int tcc = mload & (TC - 1);
    const int b   = mload >> TCLOG;
    const int tglob = t_base + t_sign * tcc;
    const long arow = (long)b * SS + tglob;
    const float* Ap = GATHER ? (A + (long)tokens[arow] * KDIM + lk)
                             : (A + arow * (long)KDIM + lk);
    const float* Wp = W + (long)(n0 + lr) * KDIM + lk;

    const int tr = tid >> 4;
    const int tn = tid & 15;

    float acc[4][4];
    #pragma unroll
    for (int i = 0; i < 4; i++)
        #pragma unroll
        for (int j = 0; j < 4; j++) acc[i][j] = 0.f;

    #pragma unroll 1
    for (int k0 = 0; k0 < KDIM; k0 += 16) {
        float4 av = *(const float4*)(Ap + k0);
        float4 bv = *(const float4*)(Wp + k0);
        As[lk + 0][lr] = av.x; As[lk + 1][lr] = av.y;
        As[lk + 2][lr] = av.z; As[lk + 3][lr] = av.w;
        Bs[lk + 0][lr] = bv.x; Bs[lk + 1][lr] = bv.y;
        Bs[lk + 2][lr] = bv.z; Bs[lk + 3][lr] = bv.w;
        __syncthreads();
        #pragma unroll
        for (int kk = 0; kk < 16; kk++) {
            float a[4], w[4];
            *(float4*)a = *(const float4*)&As[kk][tr * 4];
            *(float4*)w = *(const float4*)&Bs[kk][tn * 4];
            #pragma unroll
            for (int i = 0; i < 4; i++)
                #pragma unroll
                for (int j = 0; j < 4; j++) acc[i][j] = fmaf(a[i], w[j], acc[i][j]);
        }
        __syncthreads();
    }

    float4 bc = *(const float4*)(bias + n0 + tn * 4);
    #pragma unroll
    for (int i = 0; i < 4; i++) {
        float4 r;
        r.x = acc[i][0] + bc.x; r.y = acc[i][1] + bc.y;
        r.z = acc[i][2] + bc.z; r.w = acc[i][3] + bc.w;
        *(float4*)(out + (long)(m0 + tr * 4 + i) * G4 + n0 + tn * 4) = r;
    }
}

// ---------- split-pair LSTM scan ----------
// Grid (32 pair, 2 dir, 2 half), 512 threads (8 waves = 2/SIMD).
// Block owns h-columns [hf*128, hf*128+128) for batch rows 2p,2p+1:
// computes gate rows {m*256 + hf*128 + q} (512 of 1024), updates c,h locally.
// Cross-block: publish own 128 h-cols (x2 batch) via agent-scope hx + monotone
// flag; read peer's 128 each step. Weights: 18/64 k4 chunks in LDS (144 KB),
// 46 streamed from L2 (368 KB/step vs 880 KB unsplit).
__global__ __launch_bounds__(512, 2) void lstm_sscan(
    const float* __restrict__ xgF, const float* __restrict__ xgB, // [B][TC][1024]
    const float* __restrict__ wT,     // [2][64][1024][4]
    const float* __restrict__ bhh2,   // [2][1024]
    float* __restrict__ hout,         // [B*S][512]
    float* __restrict__ cstate,       // [2][64][256]
    float* hx,                        // [2 par][2 d][32 p][2 bb][256]
    int* flags,                       // [128] = [(d*32+p)*2+hf]
    int base, int tbF, int tbB, int doInit)
{
    const int p  = blockIdx.x;
    const int d  = blockIdx.y;
    const int hf = blockIdx.z;
    const int b0 = 2 * p, b1 = 2 * p + 1;
    const int t  = threadIdx.x;
    const int m  = t >> 7;                      // gate type 0..3
    const int j  = m * 256 + hf * 128 + (t & 127);  // global gate row
    const float* xg  = d ? xgB : xgF;
    const float* wTd = wT + (long)d * 64 * 1024 * 4;

    __shared__ float  hl[2][2][256];    // [par][bb][k]  4 KB
    __shared__ float  gl[2][512];       // [bb][local row] 4 KB
    __shared__ float4 lw[KL * 512];     // 144 KB weight cache

    // LDS weight cache: k4 in [0,KL), own 512 rows
    #pragma unroll
    for (int kk = 0; kk < KL; kk++)
        lw[kk * 512 + t] = *(const float4*)(wTd + ((long)kk * 1024 + j) * 4);

    const float bj = bhh2[d * G4 + j];

    // update-thread identity (t<256): (bb, q) -> own column hf*128+q
    const int uq = t & 127, ubb = t >> 7;
    const int ucol = hf * 128 + uq;
    const int pcol = (hf ^ 1) * 128 + uq;
    const int ub = ubb ? b1 : b0;
    float c_reg = 0.f;
    if (t < 256) {
        if (!doInit) c_reg = cstate[((long)d * BB + ub) * 256 + ucol];
        // h_{base-1} lives in hx slot parity 0 (base even); own + peer segments
        long hb = (((long)d * NPAIR + p) * 2 + ubb) * 256;  // par=0 block offset
        hl[0][ubb][ucol] = ALD(&hx[hb + ucol]);
        hl[0][ubb][pcol] = ALD(&hx[hb + pcol]);
    }
    __syncthreads();   // covers hl preload + lw fill

    const int fi  = (d * NPAIR + p) * 2 + hf;
    const int pfi = fi ^ 1;
    const long hxhalf = (long)2 * NPAIR * 2 * 256;   // parity stride

    #pragma unroll 1
    for (int tc = 0; tc < TC; ++tc) {
        const int n   = base + tc;
        const int par = n & 1;
        if (tc > 0) {
            if (t == 0) {
                long it = 0;
                while (ALD(&flags[pfi]) < n) {        // peer published h_{n-1}?
                    __builtin_amdgcn_s_sleep(2);
                    if (++it > 300000000L) break;     // bail: wrong, never hang
                }
            }
            __syncthreads();
            if (t < 256) {
                long hb = (long)par * hxhalf + (((long)d * NPAIR + p) * 2 + ubb) * 256;
                hl[par][ubb][pcol] = ALD(&hx[hb + pcol]);
            }
            __syncthreads();
        }
        float acc0 = xg[((long)(b0 * TC + tc)) * G4 + j] + bj;
        float acc1 = xg[((long)(b1 * TC + tc)) * G4 + j] + bj;
        const float4* h0 = (const float4*)hl[par][0];
        const float4* h1 = (const float4*)hl[par][1];
        // LDS-cached chunks
        #pragma unroll
        for (int kk = 0; kk < KL; kk++) {
            float4 w = lw[kk * 512 + t];
            acc0 = dot4(w, h0[kk], acc0);
            acc1 = dot4(w, h1[kk], acc1);
        }
        // L2-streamed chunks
        #pragma unroll 6
        for (int k4 = KL; k4 < 64; k4++) {
            float4 w = *(const float4*)(wTd + ((long)k4 * 1024 + j) * 4);
            acc0 = dot4(w, h0[k4], acc0);
            acc1 = dot4(w, h1[k4], acc1);
        }
        gl[0][t] = acc0;
        gl[1][t] = acc1;
        __syncthreads();
        if (t < 256) {
            // gates for col uq: i=thread uq, f=128+uq, g=256+uq, o=384+uq
            float gi = gl[ubb][uq], gf = gl[ubb][128 + uq];
            float gg = gl[ubb][256 + uq], go = gl[ubb][384 + uq];
            c_reg = sigf(gf) * c_reg + sigf(gi) * tanhfast(gg);
            float h = sigf(go) * tanhfast(c_reg);
            hl[par ^ 1][ubb][ucol] = h;
            long hb = (long)(par ^ 1) * hxhalf + (((long)d * NPAIR + p) * 2 + ubb) * 256;
            AST(&hx[hb + ucol], h);
            const int tg = d ? (tbB - tc) : (tbF + tc);
            hout[((long)(ub * SS + tg)) * 512 + d * HH + ucol] = h;
        }
        __syncthreads();   // drains vmcnt -> h stores visible before flag
        if (t == 0) AADD(&flags[fi], 1);
    }
    if (t < 256) cstate[((long)d * BB + ub) * 256 + ucol] = c_reg;
}

// ---------- emissions ----------
__global__ __launch_bounds__(256) void emissions_k(
    const float* __restrict__ h1, const float* __restrict__ clsw,
    const float* __restrict__ clsb, float* __restrict__ em)
{
    long u = (long)blockIdx.x * 256 + threadIdx.x;
    if (u >= (long)BB * SS * NC) return;
    int c = (int)(u % NC);
    long m = u / NC;
    const float4* hr = (const float4*)(h1 + m * 512);
    const float4* wr = (const float4*)(clsw + (long)c * 512);
    float s0 = 0, s1 = 0, s2 = 0, s3 = 0;
    #pragma unroll 8
    for (int q = 0; q < 128; q += 4) {
        float4 a0 = hr[q],     w0 = wr[q];
        float4 a1 = hr[q + 1], w1 = wr[q + 1];
        float4 a2 = hr[q + 2], w2 = wr[q + 2];
        float4 a3 = hr[q + 3], w3 = wr[q + 3];
        s0 += a0.x * w0.x + a0.y * w0.y + a0.z * w0.z + a0.w * w0.w;
        s1 += a1.x * w1.x + a1.y * w1.y + a1.z * w1.z + a1.w * w1.w;
        s2 += a2.x * w2.x + a2.y * w2.y + a2.z * w2.z + a2.w * w2.w;
        s3 += a3.x * w3.x + a3.y * w3.y + a3.z * w3.z + a3.w * w3.w;
    }
    em[u] = (s0 + s1) + (s2 + s3) + clsb[c];
}

// ---------- CRF log-likelihood per batch row ----------
__global__ __launch_bounds__(64) void crf_llh(
    const float* __restrict__ em, const int* __restrict__ labels,
    const int* __restrict__ mask, const float* __restrict__ start,
    const float* __restrict__ endt, const float* __restrict__ trans,
    float* __restrict__ llh)
{
    int b = blockIdx.x, j = threadIdx.x;
    bool act = j < NC;
    float tcol[NC];
    #pragma unroll
    for (int i = 0; i < NC; i++) tcol[i] = act ? trans[i * NC + j] : 0.f;
    const float* emb_ = em + (long)b * SS * NC;
    const int* lb = labels + b * SS;
    const int* mk = mask + b * SS;
    float alpha = act ? (start[j] + emb_[j]) : -1e30f;

    float num = 0.f;
    int msum = 0;
    for (int t = j; t < SS; t += 64) msum += (mk[t] != 0);
    for (int t = 1 + j; t < SS; t += 64) {
        float m = (float)mk[t];
        num += m * (trans[lb[t - 1] * NC + lb[t]] + emb_[t * NC + lb[t]]);
    }
    for (int o = 32; o > 0; o >>= 1) {
        num  += __shfl_down(num, o);
        msum += __shfl_down(msum, o);
    }
    msum = __shfl(msum, 0);

    for (int t = 1; t < SS; t++) {
        int m = mk[t];
        float emj = act ? emb_[t * NC + j] : 0.f;
        float v[NC];
        float mx = -1e30f;
        #pragma unroll
        for (int i = 0; i < NC; i++) {
            v[i] = __shfl(alpha, i) + tcol[i];
            mx = fmaxf(mx, v[i]);
        }
        float sum = 0.f;
        #pragma unroll
        for (int i = 0; i < NC; i++) sum += __expf(v[i] - mx);
        float nxt = mx + __logf(sum) + emj;
        if (m > 0 && act) alpha = nxt;
    }
    float fin = act ? alpha + endt[j] : -1e30f;
    float mx = -1e30f;
    #pragma unroll
    for (int i = 0; i < NC; i++) mx = fmaxf(mx, __shfl(fin, i));
    float s = 0.f;
    #pragma unroll
    for (int i = 0; i < NC; i++) s += __expf(__shfl(fin, i) - mx);
    float den = mx + __logf(s);
    if (j == 0) {
        int last_idx = msum - 1;
        float numer = num + start[lb[0]] + emb_[lb[0]] + endt[lb[last_idx]];
        llh[b] = numer - den;
    }
}

__global__ __launch_bounds__(64) void loss_k(const float* __restrict__ llh, float* __restrict__ out) {
    int j = threadIdx.x;
    float v = llh[j];
    for (int o = 32; o > 0; o >>= 1) v += __shfl_down(v, o);
    if (j == 0) out[0] = -v / 64.0f;
}

// ---------- Viterbi per batch row ----------
__global__ __launch_bounds__(64) void viterbi_k(
    const float* __restrict__ em, const int* __restrict__ mask,
    const float* __restrict__ start, const float* __restrict__ endt,
    const float* __restrict__ trans, float* __restrict__ outp)
{
    int b = blockIdx.x, j = threadIdx.x;
    bool act = j < NC;
    __shared__ unsigned char bp[SS][NC];
    float tcol[NC];
    #pragma unroll
    for (int i = 0; i < NC; i++) tcol[i] = act ? trans[i * NC + j] : 0.f;
    const float* emb_ = em + (long)b * SS * NC;
    const int* mk = mask + b * SS;
    float score = act ? (start[j] + emb_[j]) : -1e30f;

    for (int t = 1; t < SS; t++) {
        float best = 0.f;
        int bi = 0;
        #pragma unroll
        for (int i = 0; i < NC; i++) {
            float vv = __shfl(score, i) + tcol[i];
            if (i == 0 || vv > best) { best = vv; bi = i; }   // first-max (jnp.argmax)
        }
        int m = mk[t];
        float nxt = best + (act ? emb_[t * NC + j] : 0.f);
        if (act) {
            if (m > 0) { score = nxt; bp[t][j] = (unsigned char)bi; }
            else       { bp[t][j] = (unsigned char)j; }
        }
    }
    float fin = act ? score + endt[j] : -1e30f;
    float bestf = 0.f;
    int last = 0;
    #pragma unroll
    for (int i = 0; i < NC; i++) {
        float vv = __shfl(fin, i);
        if (i == 0 || vv > bestf) { bestf = vv; last = i; }
    }
    __syncthreads();
    if (j == 0) {
        int cur = last;
        outp[1 + (long)b * SS + (SS - 1)] = (float)cur;
        for (int t = SS - 1; t >= 1; t--) {
            cur = bp[t][cur];
            outp[1 + (long)b * SS + (t - 1)] = (float)cur;
        }
    }
}

extern "C" void kernel_launch(void* const* d_in, const int* in_sizes, int n_in,
                              void* d_out, int out_size, void* d_ws, size_t ws_size,
                              hipStream_t stream) {
    const int*   tok    = (const int*)d_in[0];
    const int*   lab    = (const int*)d_in[1];
    const int*   msk    = (const int*)d_in[2];
    const float* emb    = (const float*)d_in[3];
    const float* w_ih0  = (const float*)d_in[4];   // (2,1024,128)
    const float* w_hh0  = (const float*)d_in[5];   // (2,1024,256)
    const float* b_ih0  = (const float*)d_in[6];   // (2,1024)
    const float* b_hh0  = (const float*)d_in[7];
    const float* w_ih1  = (const float*)d_in[8];   // (2,1024,512)
    const float* w_hh1  = (const float*)d_in[9];
    const float* b_ih1  = (const float*)d_in[10];
    const float* b_hh1  = (const float*)d_in[11];
    const float* clsw   = (const float*)d_in[12];  // (9,512)
    const float* clsb   = (const float*)d_in[13];
    const float* startt = (const float*)d_in[14];
    const float* endt   = (const float*)d_in[15];
    const float* transm = (const float*)d_in[16];
    float* out = (float*)d_out;

    // ---- workspace carve (f32 elements); ~206 MB (proven footprint + 0.3 MB) ----
    size_t nH  = (size_t)BB * SS * 512;            // 16.78M each
    size_t nWT = (size_t)2 * 64 * 1024 * 4;        // 0.52M per layer
    size_t nEM = (size_t)BB * SS * NC;
    size_t nST = (size_t)2 * BB * 2 * HH;
    size_t nXG = (size_t)BB * TC * G4;             // 8.39M each dir
    size_t nHX = (size_t)2 * 2 * NPAIR * 2 * 256;  // 65536
    size_t nFL = 128;

    float* H0  = (float*)d_ws;
    float* H1  = H0 + nH;
    float* WT0 = H1 + nH;
    float* WT1 = WT0 + nWT;
    float* EM  = WT1 + nWT;
    float* ST  = EM + nEM;                          // c-state [2][64][256] (uses half)
    float* LLH = ST + nST;
    float* XGF = LLH + 64;
    float* XGB = XGF + nXG;
    float* HX  = XGB + nXG;
    int*   FLG = (int*)(HX + nHX);
    int   nZero = (int)(nHX + nFL);

    transpose_whh<<<512, 256, 0, stream>>>(w_hh0, WT0);
    transpose_whh<<<512, 256, 0, stream>>>(w_hh1, WT1);

    dim3 gg((BB * TC) / 64, G4 / 64);    // (128, 16)
    dim3 sg(NPAIR, 2, 2);                // 128 blocks, 512 threads

    // ---- layer 0 ----
    zero_k<<<(nZero + 255) / 256, 256, 0, stream>>>(HX, nZero);
    for (int c = 0; c < NCH; c++) {
        int tbF = c * TC;
        int tbB = SS - 1 - c * TC;
        gemm_xg<128, true><<<gg, 256, 0, stream>>>(emb, tok, w_ih0,              b_ih0,        XGF, tbF, +1);
        gemm_xg<128, true><<<gg, 256, 0, stream>>>(emb, tok, w_ih0 + 1024 * 128, b_ih0 + 1024, XGB, tbB, -1);
        lstm_sscan<<<sg, 512, 0, stream>>>(XGF, XGB, WT0, b_hh0, H0, ST, HX, FLG, c * TC, tbF, tbB, c == 0);
    }
    // ---- layer 1 ----
    zero_k<<<(nZero + 255) / 256, 256, 0, stream>>>(HX, nZero);
    for (int c = 0; c < NCH; c++) {
        int tbF = c * TC;
        int tbB = SS - 1 - c * TC;
        gemm_xg<512, false><<<gg, 256, 0, stream>>>(H0, nullptr, w_ih1,              b_ih1,        XGF, tbF, +1);
        gemm_xg<512, false><<<gg, 256, 0, stream>>>(H0, nullptr, w_ih1 + 1024 * 512, b_ih1 + 1024, XGB, tbB, -1);
        lstm_sscan<<<sg, 512, 0, stream>>>(XGF, XGB, WT1, b_hh1, H1, ST, HX, FLG, c * TC, tbF, tbB, c == 0);
    }

    emissions_k<<<((BB * SS * NC) + 255) / 256, 256, 0, stream>>>(H1, clsw, clsb, EM);
    crf_llh<<<BB, 64, 0, stream>>>(EM, lab, msk, startt, endt, transm, LLH);
    loss_k<<<1, 64, 0, stream>>>(LLH, out);
    viterbi_k<<<BB, 64, 0, stream>>>(EM, msk, startt, endt, transm, out);
}

// Round 13
// 5871.148 us; speedup vs baseline: 1.4354x; 1.4354x over previous
//
#include <hip/hip_runtime.h>
#include <math.h>

#define BB 64      // batch
#define SS 512     // seq len
#define EE 128     // embed dim
#define HH 256     // hidden
#define NC 9       // classes
#define G4 1024    // 4*H gates (one direction)
#define TCLOG 7
#define TC 128     // time chunk
#define NCH (SS / TC)

#define KLB 9      // k8 chunks (of 8 k) cached in LDS = 9*16KB = 144 KB
// streamed: k8 in [KLB, 32) = 23 chunks = 368 KB/step (bf16)

// ---------- activations (overflow-safe, fast) ----------
__device__ __forceinline__ float sigf(float x) {
    return 1.0f / (1.0f + __expf(-x));
}
__device__ __forceinline__ float tanhfast(float x) {
    float a = fabsf(x);
    float e = __expf(-2.0f * a);
    float t = (1.0f - e) / (1.0f + e);
    return copysignf(t, x);
}
// unpack 2 bf16 from one u32 (low ushort = even k, high = odd k)
__device__ __forceinline__ void bf2(unsigned u, float& a, float& b) {
    a = __uint_as_float(u << 16);
    b = __uint_as_float(u & 0xffff0000u);
}
__device__ __forceinline__ float dot8(uint4 w, float4 ha, float4 hb, float acc) {
    float a, b;
    bf2(w.x, a, b); acc = fmaf(a, ha.x, acc); acc = fmaf(b, ha.y, acc);
    bf2(w.y, a, b); acc = fmaf(a, ha.z, acc); acc = fmaf(b, ha.w, acc);
    bf2(w.z, a, b); acc = fmaf(a, hb.x, acc); acc = fmaf(b, hb.y, acc);
    bf2(w.w, a, b); acc = fmaf(a, hb.z, acc); acc = fmaf(b, hb.w, acc);
    return acc;
}

// ---------- transpose + bf16-pack w_hh -> wTb[dir][k8][j][8 bf16] ----------
__global__ void transpose_whhb(const float* __restrict__ whh, ushort* __restrict__ wTb) {
    // whh: [2][1024][256] f32 ; wTb: [2][32][1024][8] bf16 (16B per (dir,k8,j))
    int idx = blockIdx.x * 256 + threadIdx.x;        // over 2*32*1024
    if (idx >= 2 * 32 * 1024) return;
    int j   = idx & 1023;
    int k8  = (idx >> 10) & 31;
    int dir = idx >> 15;
    const float* src = whh + ((long)(dir * 1024 + j)) * 256 + k8 * 8;
    ushort out[8];
    #pragma unroll
    for (int i = 0; i < 8; i++) {
        unsigned u = __float_as_uint(src[i]);
        // round-to-nearest-even bf16
        u = u + 0x7fffu + ((u >> 16) & 1u);
        out[i] = (ushort)(u >> 16);
    }
    *(uint4*)(wTb + (long)idx * 8) = *(uint4*)out;
}

// ---------- tiled f32 GEMM (proven round-3): out[m][n] = A . W[n] + bias ----------
template <int KDIM, bool GATHER>
__global__ __launch_bounds__(256) void gemm_xg(
    const float* __restrict__ A, const int* __restrict__ tokens,
    const float* __restrict__ W, const float* __restrict__ bias,
    float* __restrict__ out, int t_base, int t_sign)
{
    __shared__ float As[16][68];
    __shared__ float Bs[16][68];
    const int tid = threadIdx.x;
    const int m0 = blockIdx.x * 64;
    const int n0 = blockIdx.y * 64;

    const int lr = tid >> 2;
    const int lk = (tid & 3) * 4;
    const int mload = m0 + lr;
    const int tcc = mload & (TC - 1);
    const int b   = mload >> TCLOG;
    const int tglob = t_base + t_sign * tcc;
    const long arow = (long)b * SS + tglob;
    const float* Ap = GATHER ? (A + (long)tokens[arow] * KDIM + lk)
                             : (A + arow * (long)KDIM + lk);
    const float* Wp = W + (long)(n0 + lr) * KDIM + lk;

    const int tr = tid >> 4;
    const int tn = tid & 15;

    float acc[4][4];
    #pragma unroll
    for (int i = 0; i < 4; i++)
        #pragma unroll
        for (int j = 0; j < 4; j++) acc[i][j] = 0.f;

    #pragma unroll 1
    for (int k0 = 0; k0 < KDIM; k0 += 16) {
        float4 av = *(const float4*)(Ap + k0);
        float4 bv = *(const float4*)(Wp + k0);
        As[lk + 0][lr] = av.x; As[lk + 1][lr] = av.y;
        As[lk + 2][lr] = av.z; As[lk + 3][lr] = av.w;
        Bs[lk + 0][lr] = bv.x; Bs[lk + 1][lr] = bv.y;
        Bs[lk + 2][lr] = bv.z; Bs[lk + 3][lr] = bv.w;
        __syncthreads();
        #pragma unroll
        for (int kk = 0; kk < 16; kk++) {
            float a[4], w[4];
            *(float4*)a = *(const float4*)&As[kk][tr * 4];
            *(float4*)w = *(const float4*)&Bs[kk][tn * 4];
            #pragma unroll
            for (int i = 0; i < 4; i++)
                #pragma unroll
                for (int j = 0; j < 4; j++) acc[i][j] = fmaf(a[i], w[j], acc[i][j]);
        }
        __syncthreads();
    }

    float4 bc = *(const float4*)(bias + n0 + tn * 4);
    #pragma unroll
    for (int i = 0; i < 4; i++) {
        float4 r;
        r.x = acc[i][0] + bc.x; r.y = acc[i][1] + bc.y;
        r.z = acc[i][2] + bc.z; r.w = acc[i][3] + bc.w;
        *(float4*)(out + (long)(m0 + tr * 4 + i) * G4 + n0 + tn * 4) = r;
    }
}

// ---------- bf16-weight LSTM scan (round-8 structure) ----------
// Grid (64 batch, 2 dir), 1024 threads (16 waves = 4/SIMD).
// Thread j owns gate row j: 32 uint4 (8 bf16 each).
//   k8 [0,KLB)   -> LDS (144 KB)
//   k8 [KLB,32)  -> streamed from L2 (368 KB/step)
// gl exchange + double-buffered h: 2 barriers/step.
__global__ __launch_bounds__(1024, 4) void lstm_bscan(
    const float* __restrict__ xgF, const float* __restrict__ xgB, // [B][TC][1024]
    const ushort* __restrict__ wTb,   // [2][32][1024][8 bf16]
    const float* __restrict__ bhh2,   // [2][1024]
    float* __restrict__ hout,         // [B*S][512]
    float* __restrict__ state,        // [2][B][2][256]
    int tbF, int tbB, int doInit)
{
    const int b = blockIdx.x;
    const int d = blockIdx.y;
    const int j = threadIdx.x;
    const float* xg = (d ? xgB : xgF) + (long)b * TC * G4 + j;
    const uint4* wTd = (const uint4*)(wTb + (long)d * 32 * 1024 * 8);

    __shared__ float4 hl[2][64];        // 2 KB double-buffered h
    __shared__ float  gl[G4];           // 4 KB gate exchange
    __shared__ uint4  lwb[KLB * 1024];  // 144 KB bf16 weight cache

    // ---- LDS weight cache: k8 in [0,KLB) ----
    #pragma unroll
    for (int k8 = 0; k8 < KLB; k8++)
        lwb[k8 * 1024 + j] = wTd[(long)k8 * 1024 + j];

    const float bj = bhh2[d * G4 + j];
    float c_reg = 0.f;
    if (doInit) {
        if (j < HH) ((float*)hl[0])[j] = 0.f;
    } else {
        if (j < HH) {
            ((float*)hl[0])[j] = state[((d * BB + b) * 2 + 0) * HH + j];
            c_reg               = state[((d * BB + b) * 2 + 1) * HH + j];
        }
    }
    __syncthreads();   // covers hl init + lwb fill

    #pragma unroll 1
    for (int tc = 0; tc < TC; ++tc) {
        const int rb = tc & 1;
        const float4* hcur = hl[rb];
        float acc = xg[(long)tc * G4] + bj;

        // LDS-cached chunks
        #pragma unroll
        for (int k8 = 0; k8 < KLB; k8++)
            acc = dot8(lwb[k8 * 1024 + j], hcur[2 * k8], hcur[2 * k8 + 1], acc);
        // L2-streamed chunks
        #pragma unroll 6
        for (int k8 = KLB; k8 < 32; k8++) {
            uint4 w = wTd[(long)k8 * 1024 + j];
            acc = dot8(w, hcur[2 * k8], hcur[2 * k8 + 1], acc);
        }

        gl[j] = acc;
        __syncthreads();
        if (j < HH) {
            float gi = gl[j], gf = gl[j + 256], gg = gl[j + 512], go = gl[j + 768];
            c_reg = sigf(gf) * c_reg + sigf(gi) * tanhfast(gg);
            float h = sigf(go) * tanhfast(c_reg);
            ((float*)hl[rb ^ 1])[j] = h;
            const int t = d ? (tbB - tc) : (tbF + tc);
            hout[((long)(b * SS + t)) * 512 + d * HH + j] = h;
        }
        __syncthreads();
    }

    if (j < HH) {
        state[((d * BB + b) * 2 + 0) * HH + j] = ((float*)hl[TC & 1])[j];
        state[((d * BB + b) * 2 + 1) * HH + j] = c_reg;
    }
}

// ---------- emissions ----------
__global__ __launch_bounds__(256) void emissions_k(
    const float* __restrict__ h1, const float* __restrict__ clsw,
    const float* __restrict__ clsb, float* __restrict__ em)
{
    long u = (long)blockIdx.x * 256 + threadIdx.x;
    if (u >= (long)BB * SS * NC) return;
    int c = (int)(u % NC);
    long m = u / NC;
    const float4* hr = (const float4*)(h1 + m * 512);
    const float4* wr = (const float4*)(clsw + (long)c * 512);
    float s0 = 0, s1 = 0, s2 = 0, s3 = 0;
    #pragma unroll 8
    for (int q = 0; q < 128; q += 4) {
        float4 a0 = hr[q],     w0 = wr[q];
        float4 a1 = hr[q + 1], w1 = wr[q + 1];
        float4 a2 = hr[q + 2], w2 = wr[q + 2];
        float4 a3 = hr[q + 3], w3 = wr[q + 3];
        s0 += a0.x * w0.x + a0.y * w0.y + a0.z * w0.z + a0.w * w0.w;
        s1 += a1.x * w1.x + a1.y * w1.y + a1.z * w1.z + a1.w * w1.w;
        s2 += a2.x * w2.x + a2.y * w2.y + a2.z * w2.z + a2.w * w2.w;
        s3 += a3.x * w3.x + a3.y * w3.y + a3.z * w3.z + a3.w * w3.w;
    }
    em[u] = (s0 + s1) + (s2 + s3) + clsb[c];
}

// ---------- CRF log-likelihood per batch row ----------
__global__ __launch_bounds__(64) void crf_llh(
    const float* __restrict__ em, const int* __restrict__ labels,
    const int* __restrict__ mask, const float* __restrict__ start,
    const float* __restrict__ endt, const float* __restrict__ trans,
    float* __restrict__ llh)
{
    int b = blockIdx.x, j = threadIdx.x;
    bool act = j < NC;
    float tcol[NC];
    #pragma unroll
    for (int i = 0; i < NC; i++) tcol[i] = act ? trans[i * NC + j] : 0.f;
    const float* emb_ = em + (long)b * SS * NC;
    const int* lb = labels + b * SS;
    const int* mk = mask + b * SS;
    float alpha = act ? (start[j] + emb_[j]) : -1e30f;

    float num = 0.f;
    int msum = 0;
    for (int t = j; t < SS; t += 64) msum += (mk[t] != 0);
    for (int t = 1 + j; t < SS; t += 64) {
        float m = (float)mk[t];
        num += m * (trans[lb[t - 1] * NC + lb[t]] + emb_[t * NC + lb[t]]);
    }
    for (int o = 32; o > 0; o >>= 1) {
        num  += __shfl_down(num, o);
        msum += __shfl_down(msum, o);
    }
    msum = __shfl(msum, 0);

    for (int t = 1; t < SS; t++) {
        int m = mk[t];
        float emj = act ? emb_[t * NC + j] : 0.f;
        float v[NC];
        float mx = -1e30f;
        #pragma unroll
        for (int i = 0; i < NC; i++) {
            v[i] = __shfl(alpha, i) + tcol[i];
            mx = fmaxf(mx, v[i]);
        }
        float sum = 0.f;
        #pragma unroll
        for (int i = 0; i < NC; i++) sum += __expf(v[i] - mx);
        float nxt = mx + __logf(sum) + emj;
        if (m > 0 && act) alpha = nxt;
    }
    float fin = act ? alpha + endt[j] : -1e30f;
    float mx = -1e30f;
    #pragma unroll
    for (int i = 0; i < NC; i++) mx = fmaxf(mx, __shfl(fin, i));
    float s = 0.f;
    #pragma unroll
    for (int i = 0; i < NC; i++) s += __expf(__shfl(fin, i) - mx);
    float den = mx + __logf(s);
    if (j == 0) {
        int last_idx = msum - 1;
        float numer = num + start[lb[0]] + emb_[lb[0]] + endt[lb[last_idx]];
        llh[b] = numer - den;
    }
}

__global__ __launch_bounds__(64) void loss_k(const float* __restrict__ llh, float* __restrict__ out) {
    int j = threadIdx.x;
    float v = llh[j];
    for (int o = 32; o > 0; o >>= 1) v += __shfl_down(v, o);
    if (j == 0) out[0] = -v / 64.0f;
}

// ---------- Viterbi per batch row ----------
__global__ __launch_bounds__(64) void viterbi_k(
    const float* __restrict__ em, const int* __restrict__ mask,
    const float* __restrict__ start, const float* __restrict__ endt,
    const float* __restrict__ trans, float* __restrict__ outp)
{
    int b = blockIdx.x, j = threadIdx.x;
    bool act = j < NC;
    __shared__ unsigned char bp[SS][NC];
    float tcol[NC];
    #pragma unroll
    for (int i = 0; i < NC; i++) tcol[i] = act ? trans[i * NC + j] : 0.f;
    const float* emb_ = em + (long)b * SS * NC;
    const int* mk = mask + b * SS;
    float score = act ? (start[j] + emb_[j]) : -1e30f;

    for (int t = 1; t < SS; t++) {
        float best = 0.f;
        int bi = 0;
        #pragma unroll
        for (int i = 0; i < NC; i++) {
            float vv = __shfl(score, i) + tcol[i];
            if (i == 0 || vv > best) { best = vv; bi = i; }   // first-max (jnp.argmax)
        }
        int m = mk[t];
        float nxt = best + (act ? emb_[t * NC + j] : 0.f);
        if (act) {
            if (m > 0) { score = nxt; bp[t][j] = (unsigned char)bi; }
            else       { bp[t][j] = (unsigned char)j; }
        }
    }
    float fin = act ? score + endt[j] : -1e30f;
    float bestf = 0.f;
    int last = 0;
    #pragma unroll
    for (int i = 0; i < NC; i++) {
        float vv = __shfl(fin, i);
        if (i == 0 || vv > bestf) { bestf = vv; last = i; }
    }
    __syncthreads();
    if (j == 0) {
        int cur = last;
        outp[1 + (long)b * SS + (SS - 1)] = (float)cur;
        for (int t = SS - 1; t >= 1; t--) {
            cur = bp[t][cur];
            outp[1 + (long)b * SS + (t - 1)] = (float)cur;
        }
    }
}

extern "C" void kernel_launch(void* const* d_in, const int* in_sizes, int n_in,
                              void* d_out, int out_size, void* d_ws, size_t ws_size,
                              hipStream_t stream) {
    const int*   tok    = (const int*)d_in[0];
    const int*   lab    = (const int*)d_in[1];
    const int*   msk    = (const int*)d_in[2];
    const float* emb    = (const float*)d_in[3];
    const float* w_ih0  = (const float*)d_in[4];   // (2,1024,128)
    const float* w_hh0  = (const float*)d_in[5];   // (2,1024,256)
    const float* b_ih0  = (const float*)d_in[6];   // (2,1024)
    const float* b_hh0  = (const float*)d_in[7];
    const float* w_ih1  = (const float*)d_in[8];   // (2,1024,512)
    const float* w_hh1  = (const float*)d_in[9];
    const float* b_ih1  = (const float*)d_in[10];
    const float* b_hh1  = (const float*)d_in[11];
    const float* clsw   = (const float*)d_in[12];  // (9,512)
    const float* clsb   = (const float*)d_in[13];
    const float* startt = (const float*)d_in[14];
    const float* endt   = (const float*)d_in[15];
    const float* transm = (const float*)d_in[16];
    float* out = (float*)d_out;

    // ---- workspace carve (f32 elements); ~205 MB (round-3-proven footprint) ----
    size_t nH  = (size_t)BB * SS * 512;            // 16.78M each
    size_t nWT = (size_t)2 * 64 * 1024 * 4;        // 0.52M floats per layer (bf16 uses half)
    size_t nEM = (size_t)BB * SS * NC;
    size_t nST = (size_t)2 * BB * 2 * HH;
    size_t nXG = (size_t)BB * TC * G4;             // 8.39M each dir

    float* H0  = (float*)d_ws;
    float* H1  = H0 + nH;
    float* WT0 = H1 + nH;
    float* WT1 = WT0 + nWT;
    float* EM  = WT1 + nWT;
    float* ST  = EM + nEM;
    float* LLH = ST + nST;
    float* XGF = LLH + 64;
    float* XGB = XGF + nXG;

    ushort* WB0 = (ushort*)WT0;    // [2][32][1024][8 bf16] = 1 MB
    ushort* WB1 = (ushort*)WT1;

    transpose_whhb<<<256, 256, 0, stream>>>(w_hh0, WB0);
    transpose_whhb<<<256, 256, 0, stream>>>(w_hh1, WB1);

    dim3 gg((BB * TC) / 64, G4 / 64);    // (128, 16)
    dim3 rg(BB, 2);                      // 128 blocks, 1024 threads

    // ---- layer 0 ----
    for (int c = 0; c < NCH; c++) {
        int tbF = c * TC;
        int tbB = SS - 1 - c * TC;
        gemm_xg<128, true><<<gg, 256, 0, stream>>>(emb, tok, w_ih0,              b_ih0,        XGF, tbF, +1);
        gemm_xg<128, true><<<gg, 256, 0, stream>>>(emb, tok, w_ih0 + 1024 * 128, b_ih0 + 1024, XGB, tbB, -1);
        lstm_bscan<<<rg, 1024, 0, stream>>>(XGF, XGB, WB0, b_hh0, H0, ST, tbF, tbB, c == 0);
    }
    // ---- layer 1 ----
    for (int c = 0; c < NCH; c++) {
        int tbF = c * TC;
        int tbB = SS - 1 - c * TC;
        gemm_xg<512, false><<<gg, 256, 0, stream>>>(H0, nullptr, w_ih1,              b_ih1,        XGF, tbF, +1);
        gemm_xg<512, false><<<gg, 256, 0, stream>>>(H0, nullptr, w_ih1 + 1024 * 512, b_ih1 + 1024, XGB, tbB, -1);
        lstm_bscan<<<rg, 1024, 0, stream>>>(XGF, XGB, WB1, b_hh1, H1, ST, tbF, tbB, c == 0);
    }

    emissions_k<<<((BB * SS * NC) + 255) / 256, 256, 0, stream>>>(H1, clsw, clsb, EM);
    crf_llh<<<BB, 64, 0, stream>>>(EM, lab, msk, startt, endt, transm, LLH);
    loss_k<<<1, 64, 0, stream>>>(LLH, out);
    viterbi_k<<<BB, 64, 0, stream>>>(EM, msk, startt, endt, transm, out);
}

// Round 14
// 5252.509 us; speedup vs baseline: 1.6045x; 1.1178x over previous
//
#include <hip/hip_runtime.h>
#include <math.h>

#define BB 64      // batch
#define SS 512     // seq len
#define EE 128     // embed dim
#define HH 256     // hidden
#define NC 9       // classes
#define G4 1024    // 4*H gates (one direction)
#define TCLOG 7
#define TC 128     // time chunk
#define NCH (SS / TC)

#define KLB 9      // k8 chunks (of 8 k) cached in LDS = 144 KB
// streamed: k8 in [KLB, 32) = 23 chunks = 368 KB/step (f16)

typedef _Float16 half2v __attribute__((ext_vector_type(2)));

// ---------- activations (overflow-safe, fast) ----------
__device__ __forceinline__ float sigf(float x) {
    return 1.0f / (1.0f + __expf(-x));
}
__device__ __forceinline__ float tanhfast(float x) {
    float a = fabsf(x);
    float e = __expf(-2.0f * a);
    float t = (1.0f - e) / (1.0f + e);
    return copysignf(t, x);
}
// 8 f16 MACs via 4x v_dot2_f32_f16 (f32 accumulate)
__device__ __forceinline__ float dot8h(uint4 w, uint4 h, float acc) {
    acc = __builtin_amdgcn_fdot2(__builtin_bit_cast(half2v, w.x),
                                 __builtin_bit_cast(half2v, h.x), acc, false);
    acc = __builtin_amdgcn_fdot2(__builtin_bit_cast(half2v, w.y),
                                 __builtin_bit_cast(half2v, h.y), acc, false);
    acc = __builtin_amdgcn_fdot2(__builtin_bit_cast(half2v, w.z),
                                 __builtin_bit_cast(half2v, h.z), acc, false);
    acc = __builtin_amdgcn_fdot2(__builtin_bit_cast(half2v, w.w),
                                 __builtin_bit_cast(half2v, h.w), acc, false);
    return acc;
}

// ---------- transpose + f16-pack w_hh -> wTh[dir][k8][j][8 f16] ----------
__global__ void transpose_whhh(const float* __restrict__ whh, ushort* __restrict__ wTh) {
    // whh: [2][1024][256] f32 ; wTh: [2][32][1024][8] f16 (16B per (dir,k8,j))
    int idx = blockIdx.x * 256 + threadIdx.x;        // over 2*32*1024
    if (idx >= 2 * 32 * 1024) return;
    int j   = idx & 1023;
    int k8  = (idx >> 10) & 31;
    int dir = idx >> 15;
    const float* src = whh + ((long)(dir * 1024 + j)) * 256 + k8 * 8;
    _Float16 o[8];
    #pragma unroll
    for (int i = 0; i < 8; i++) o[i] = (_Float16)src[i];   // v_cvt_f16_f32 (RNE)
    *(uint4*)(wTh + (long)idx * 8) = *(uint4*)o;
}

// ---------- tiled f32 GEMM (proven round-3): out[m][n] = A . W[n] + bias ----------
template <int KDIM, bool GATHER>
__global__ __launch_bounds__(256) void gemm_xg(
    const float* __restrict__ A, const int* __restrict__ tokens,
    const float* __restrict__ W, const float* __restrict__ bias,
    float* __restrict__ out, int t_base, int t_sign)
{
    __shared__ float As[16][68];
    __shared__ float Bs[16][68];
    const int tid = threadIdx.x;
    const int m0 = blockIdx.x * 64;
    const int n0 = blockIdx.y * 64;

    const int lr = tid >> 2;
    const int lk = (tid & 3) * 4;
    const int mload = m0 + lr;
    const int tcc = mload & (TC - 1);
    const int b   = mload >> TCLOG;
    const int tglob = t_base + t_sign * tcc;
    const long arow = (long)b * SS + tglob;
    const float* Ap = GATHER ? (A + (long)tokens[arow] * KDIM + lk)
                             : (A + arow * (long)KDIM + lk);
    const float* Wp = W + (long)(n0 + lr) * KDIM + lk;

    const int tr = tid >> 4;
    const int tn = tid & 15;

    float acc[4][4];
    #pragma unroll
    for (int i = 0; i < 4; i++)
        #pragma unroll
        for (int j = 0; j < 4; j++) acc[i][j] = 0.f;

    #pragma unroll 1
    for (int k0 = 0; k0 < KDIM; k0 += 16) {
        float4 av = *(const float4*)(Ap + k0);
        float4 bv = *(const float4*)(Wp + k0);
        As[lk + 0][lr] = av.x; As[lk + 1][lr] = av.y;
        As[lk + 2][lr] = av.z; As[lk + 3][lr] = av.w;
        Bs[lk + 0][lr] = bv.x; Bs[lk + 1][lr] = bv.y;
        Bs[lk + 2][lr] = bv.z; Bs[lk + 3][lr] = bv.w;
        __syncthreads();
        #pragma unroll
        for (int kk = 0; kk < 16; kk++) {
            float a[4], w[4];
            *(float4*)a = *(const float4*)&As[kk][tr * 4];
            *(float4*)w = *(const float4*)&Bs[kk][tn * 4];
            #pragma unroll
            for (int i = 0; i < 4; i++)
                #pragma unroll
                for (int j = 0; j < 4; j++) acc[i][j] = fmaf(a[i], w[j], acc[i][j]);
        }
        __syncthreads();
    }

    float4 bc = *(const float4*)(bias + n0 + tn * 4);
    #pragma unroll
    for (int i = 0; i < 4; i++) {
        float4 r;
        r.x = acc[i][0] + bc.x; r.y = acc[i][1] + bc.y;
        r.z = acc[i][2] + bc.z; r.w = acc[i][3] + bc.w;
        *(float4*)(out + (long)(m0 + tr * 4 + i) * G4 + n0 + tn * 4) = r;
    }
}

// ---------- f16-dot2 LSTM scan (round-8/13 structure) ----------
// Grid (64 batch, 2 dir), 1024 threads (16 waves = 4/SIMD).
// Thread j owns gate row j: 32 uint4 (8 f16 each).
//   k8 [0,KLB)   -> LDS (144 KB)
//   k8 [KLB,32)  -> streamed from L2 (368 KB/step)
// h published as packed f16 (512 B/buffer); recurrence c and hout stay f32.
__global__ __launch_bounds__(1024, 4) void lstm_hscan(
    const float* __restrict__ xgF, const float* __restrict__ xgB, // [B][TC][1024]
    const ushort* __restrict__ wTh,   // [2][32][1024][8 f16]
    const float* __restrict__ bhh2,   // [2][1024]
    float* __restrict__ hout,         // [B*S][512]
    float* __restrict__ state,        // [2][B][2][256]
    int tbF, int tbB, int doInit)
{
    const int b = blockIdx.x;
    const int d = blockIdx.y;
    const int j = threadIdx.x;
    const float* xg = (d ? xgB : xgF) + (long)b * TC * G4 + j;
    const uint4* wTd = (const uint4*)(wTh + (long)d * 32 * 1024 * 8);

    __shared__ __align__(16) _Float16 hl[2][256];   // 1 KB double-buffered f16 h
    __shared__ float gl[G4];                        // 4 KB gate exchange
    __shared__ uint4 lwb[KLB * 1024];               // 144 KB f16 weight cache

    // ---- LDS weight cache: k8 in [0,KLB) ----
    #pragma unroll
    for (int k8 = 0; k8 < KLB; k8++)
        lwb[k8 * 1024 + j] = wTd[(long)k8 * 1024 + j];

    const float bj = bhh2[d * G4 + j];
    float c_reg = 0.f, h_reg = 0.f;
    if (j < HH) {
        if (doInit) {
            hl[0][j] = (_Float16)0.f;
        } else {
            h_reg = state[((d * BB + b) * 2 + 0) * HH + j];
            c_reg = state[((d * BB + b) * 2 + 1) * HH + j];
            hl[0][j] = (_Float16)h_reg;
        }
    }
    __syncthreads();   // covers hl init + lwb fill

    #pragma unroll 1
    for (int tc = 0; tc < TC; ++tc) {
        const int rb = tc & 1;
        const uint4* hcur = (const uint4*)hl[rb];   // 32 x 16B (8 f16 each)
        float acc = xg[(long)tc * G4] + bj;

        // LDS-cached chunks
        #pragma unroll
        for (int k8 = 0; k8 < KLB; k8++)
            acc = dot8h(lwb[k8 * 1024 + j], hcur[k8], acc);
        // L2-streamed chunks
        #pragma unroll 6
        for (int k8 = KLB; k8 < 32; k8++)
            acc = dot8h(wTd[(long)k8 * 1024 + j], hcur[k8], acc);

        gl[j] = acc;
        __syncthreads();
        if (j < HH) {
            float gi = gl[j], gf = gl[j + 256], gg = gl[j + 512], go = gl[j + 768];
            c_reg = sigf(gf) * c_reg + sigf(gi) * tanhfast(gg);
            float h = sigf(go) * tanhfast(c_reg);
            h_reg = h;
            hl[rb ^ 1][j] = (_Float16)h;
            const int t = d ? (tbB - tc) : (tbF + tc);
            hout[((long)(b * SS + t)) * 512 + d * HH + j] = h;   // unrounded f32
        }
        __syncthreads();
    }

    if (j < HH) {
        state[((d * BB + b) * 2 + 0) * HH + j] = h_reg;
        state[((d * BB + b) * 2 + 1) * HH + j] = c_reg;
    }
}

// ---------- emissions ----------
__global__ __launch_bounds__(256) void emissions_k(
    const float* __restrict__ h1, const float* __restrict__ clsw,
    const float* __restrict__ clsb, float* __restrict__ em)
{
    long u = (long)blockIdx.x * 256 + threadIdx.x;
    if (u >= (long)BB * SS * NC) return;
    int c = (int)(u % NC);
    long m = u / NC;
    const float4* hr = (const float4*)(h1 + m * 512);
    const float4* wr = (const float4*)(clsw + (long)c * 512);
    float s0 = 0, s1 = 0, s2 = 0, s3 = 0;
    #pragma unroll 8
    for (int q = 0; q < 128; q += 4) {
        float4 a0 = hr[q],     w0 = wr[q];
        float4 a1 = hr[q + 1], w1 = wr[q + 1];
        float4 a2 = hr[q + 2], w2 = wr[q + 2];
        float4 a3 = hr[q + 3], w3 = wr[q + 3];
        s0 += a0.x * w0.x + a0.y * w0.y + a0.z * w0.z + a0.w * w0.w;
        s1 += a1.x * w1.x + a1.y * w1.y + a1.z * w1.z + a1.w * w1.w;
        s2 += a2.x * w2.x + a2.y * w2.y + a2.z * w2.z + a2.w * w2.w;
        s3 += a3.x * w3.x + a3.y * w3.y + a3.z * w3.z + a3.w * w3.w;
    }
    em[u] = (s0 + s1) + (s2 + s3) + clsb[c];
}

// ---------- CRF log-likelihood per batch row ----------
__global__ __launch_bounds__(64) void crf_llh(
    const float* __restrict__ em, const int* __restrict__ labels,
    const int* __restrict__ mask, const float* __restrict__ start,
    const float* __restrict__ endt, const float* __restrict__ trans,
    float* __restrict__ llh)
{
    int b = blockIdx.x, j = threadIdx.x;
    bool act = j < NC;
    float tcol[NC];
    #pragma unroll
    for (int i = 0; i < NC; i++) tcol[i] = act ? trans[i * NC + j] : 0.f;
    const float* emb_ = em + (long)b * SS * NC;
    const int* lb = labels + b * SS;
    const int* mk = mask + b * SS;
    float alpha = act ? (start[j] + emb_[j]) : -1e30f;

    float num = 0.f;
    int msum = 0;
    for (int t = j; t < SS; t += 64) msum += (mk[t] != 0);
    for (int t = 1 + j; t < SS; t += 64) {
        float m = (float)mk[t];
        num += m * (trans[lb[t - 1] * NC + lb[t]] + emb_[t * NC + lb[t]]);
    }
    for (int o = 32; o > 0; o >>= 1) {
        num  += __shfl_down(num, o);
        msum += __shfl_down(msum, o);
    }
    msum = __shfl(msum, 0);

    for (int t = 1; t < SS; t++) {
        int m = mk[t];
        float emj = act ? emb_[t * NC + j] : 0.f;
        float v[NC];
        float mx = -1e30f;
        #pragma unroll
        for (int i = 0; i < NC; i++) {
            v[i] = __shfl(alpha, i) + tcol[i];
            mx = fmaxf(mx, v[i]);
        }
        float sum = 0.f;
        #pragma unroll
        for (int i = 0; i < NC; i++) sum += __expf(v[i] - mx);
        float nxt = mx + __logf(sum) + emj;
        if (m > 0 && act) alpha = nxt;
    }
    float fin = act ? alpha + endt[j] : -1e30f;
    float mx = -1e30f;
    #pragma unroll
    for (int i = 0; i < NC; i++) mx = fmaxf(mx, __shfl(fin, i));
    float s = 0.f;
    #pragma unroll
    for (int i = 0; i < NC; i++) s += __expf(__shfl(fin, i) - mx);
    float den = mx + __logf(s);
    if (j == 0) {
        int last_idx = msum - 1;
        float numer = num + start[lb[0]] + emb_[lb[0]] + endt[lb[last_idx]];
        llh[b] = numer - den;
    }
}

__global__ __launch_bounds__(64) void loss_k(const float* __restrict__ llh, float* __restrict__ out) {
    int j = threadIdx.x;
    float v = llh[j];
    for (int o = 32; o > 0; o >>= 1) v += __shfl_down(v, o);
    if (j == 0) out[0] = -v / 64.0f;
}

// ---------- Viterbi per batch row ----------
__global__ __launch_bounds__(64) void viterbi_k(
    const float* __restrict__ em, const int* __restrict__ mask,
    const float* __restrict__ start, const float* __restrict__ endt,
    const float* __restrict__ trans, float* __restrict__ outp)
{
    int b = blockIdx.x, j = threadIdx.x;
    bool act = j < NC;
    __shared__ unsigned char bp[SS][NC];
    float tcol[NC];
    #pragma unroll
    for (int i = 0; i < NC; i++) tcol[i] = act ? trans[i * NC + j] : 0.f;
    const float* emb_ = em + (long)b * SS * NC;
    const int* mk = mask + b * SS;
    float score = act ? (start[j] + emb_[j]) : -1e30f;

    for (int t = 1; t < SS; t++) {
        float best = 0.f;
        int bi = 0;
        #pragma unroll
        for (int i = 0; i < NC; i++) {
            float vv = __shfl(score, i) + tcol[i];
            if (i == 0 || vv > best) { best = vv; bi = i; }   // first-max (jnp.argmax)
        }
        int m = mk[t];
        float nxt = best + (act ? emb_[t * NC + j] : 0.f);
        if (act) {
            if (m > 0) { score = nxt; bp[t][j] = (unsigned char)bi; }
            else       { bp[t][j] = (unsigned char)j; }
        }
    }
    float fin = act ? score + endt[j] : -1e30f;
    float bestf = 0.f;
    int last = 0;
    #pragma unroll
    for (int i = 0; i < NC; i++) {
        float vv = __shfl(fin, i);
        if (i == 0 || vv > bestf) { bestf = vv; last = i; }
    }
    __syncthreads();
    if (j == 0) {
        int cur = last;
        outp[1 + (long)b * SS + (SS - 1)] = (float)cur;
        for (int t = SS - 1; t >= 1; t--) {
            cur = bp[t][cur];
            outp[1 + (long)b * SS + (t - 1)] = (float)cur;
        }
    }
}

extern "C" void kernel_launch(void* const* d_in, const int* in_sizes, int n_in,
                              void* d_out, int out_size, void* d_ws, size_t ws_size,
                              hipStream_t stream) {
    const int*   tok    = (const int*)d_in[0];
    const int*   lab    = (const int*)d_in[1];
    const int*   msk    = (const int*)d_in[2];
    const float* emb    = (const float*)d_in[3];
    const float* w_ih0  = (const float*)d_in[4];   // (2,1024,128)
    const float* w_hh0  = (const float*)d_in[5];   // (2,1024,256)
    const float* b_ih0  = (const float*)d_in[6];   // (2,1024)
    const float* b_hh0  = (const float*)d_in[7];
    const float* w_ih1  = (const float*)d_in[8];   // (2,1024,512)
    const float* w_hh1  = (const float*)d_in[9];
    const float* b_ih1  = (const float*)d_in[10];
    const float* b_hh1  = (const float*)d_in[11];
    const float* clsw   = (const float*)d_in[12];  // (9,512)
    const float* clsb   = (const float*)d_in[13];
    const float* startt = (const float*)d_in[14];
    const float* endt   = (const float*)d_in[15];
    const float* transm = (const float*)d_in[16];
    float* out = (float*)d_out;

    // ---- workspace carve (f32 elements); ~205 MB (round-3-proven footprint) ----
    size_t nH  = (size_t)BB * SS * 512;            // 16.78M each
    size_t nWT = (size_t)2 * 64 * 1024 * 4;        // 0.52M floats per layer (f16 uses half)
    size_t nEM = (size_t)BB * SS * NC;
    size_t nST = (size_t)2 * BB * 2 * HH;
    size_t nXG = (size_t)BB * TC * G4;             // 8.39M each dir

    float* H0  = (float*)d_ws;
    float* H1  = H0 + nH;
    float* WT0 = H1 + nH;
    float* WT1 = WT0 + nWT;
    float* EM  = WT1 + nWT;
    float* ST  = EM + nEM;
    float* LLH = ST + nST;
    float* XGF = LLH + 64;
    float* XGB = XGF + nXG;

    ushort* WH0 = (ushort*)WT0;    // [2][32][1024][8 f16] = 1 MB
    ushort* WH1 = (ushort*)WT1;

    transpose_whhh<<<256, 256, 0, stream>>>(w_hh0, WH0);
    transpose_whhh<<<256, 256, 0, stream>>>(w_hh1, WH1);

    dim3 gg((BB * TC) / 64, G4 / 64);    // (128, 16)
    dim3 rg(BB, 2);                      // 128 blocks, 1024 threads

    // ---- layer 0 ----
    for (int c = 0; c < NCH; c++) {
        int tbF = c * TC;
        int tbB = SS - 1 - c * TC;
        gemm_xg<128, true><<<gg, 256, 0, stream>>>(emb, tok, w_ih0,              b_ih0,        XGF, tbF, +1);
        gemm_xg<128, true><<<gg, 256, 0, stream>>>(emb, tok, w_ih0 + 1024 * 128, b_ih0 + 1024, XGB, tbB, -1);
        lstm_hscan<<<rg, 1024, 0, stream>>>(XGF, XGB, WH0, b_hh0, H0, ST, tbF, tbB, c == 0);
    }
    // ---- layer 1 ----
    for (int c = 0; c < NCH; c++) {
        int tbF = c * TC;
        int tbB = SS - 1 - c * TC;
        gemm_xg<512, false><<<gg, 256, 0, stream>>>(H0, nullptr, w_ih1,              b_ih1,        XGF, tbF, +1);
        gemm_xg<512, false><<<gg, 256, 0, stream>>>(H0, nullptr, w_ih1 + 1024 * 512, b_ih1 + 1024, XGB, tbB, -1);
        lstm_hscan<<<rg, 1024, 0, stream>>>(XGF, XGB, WH1, b_hh1, H1, ST, tbF, tbB, c == 0);
    }

    emissions_k<<<((BB * SS * NC) + 255) / 256, 256, 0, stream>>>(H1, clsw, clsb, EM);
    crf_llh<<<BB, 64, 0, stream>>>(EM, lab, msk, startt, endt, transm, LLH);
    loss_k<<<1, 64, 0, stream>>>(LLH, out);
    viterbi_k<<<BB, 64, 0, stream>>>(EM, msk, startt, endt, transm, out);
}

// Round 15
// 4902.278 us; speedup vs baseline: 1.7191x; 1.0714x over previous
//
#include <hip/hip_runtime.h>
#include <math.h>

#define BB 64      // batch
#define SS 512     // seq len
#define EE 128     // embed dim
#define HH 256     // hidden
#define NC 9       // classes
#define G4 1024    // 4*H gates (one direction)
#define TCLOG 7
#define TC 128     // time chunk
#define NCH (SS / TC)

#define KLB 9      // k8 chunks (of 8 k) cached in LDS = 144 KB (scan)

typedef _Float16 half2v __attribute__((ext_vector_type(2)));

// ---------- activations (overflow-safe, fast) ----------
__device__ __forceinline__ float sigf(float x) {
    return 1.0f / (1.0f + __expf(-x));
}
__device__ __forceinline__ float tanhfast(float x) {
    float a = fabsf(x);
    float e = __expf(-2.0f * a);
    float t = (1.0f - e) / (1.0f + e);
    return copysignf(t, x);
}
// 8 f16 MACs via 4x v_dot2_f32_f16 (f32 accumulate)
__device__ __forceinline__ float dot8h(uint4 w, uint4 h, float acc) {
    acc = __builtin_amdgcn_fdot2(__builtin_bit_cast(half2v, w.x),
                                 __builtin_bit_cast(half2v, h.x), acc, false);
    acc = __builtin_amdgcn_fdot2(__builtin_bit_cast(half2v, w.y),
                                 __builtin_bit_cast(half2v, h.y), acc, false);
    acc = __builtin_amdgcn_fdot2(__builtin_bit_cast(half2v, w.z),
                                 __builtin_bit_cast(half2v, h.z), acc, false);
    acc = __builtin_amdgcn_fdot2(__builtin_bit_cast(half2v, w.w),
                                 __builtin_bit_cast(half2v, h.w), acc, false);
    return acc;
}
__device__ __forceinline__ ushort f16b(float x) {
    return __builtin_bit_cast(ushort, (_Float16)x);
}

// ---------- transpose + f16-pack w_hh -> wTh[dir][k8][j][8 f16] ----------
__global__ void transpose_whhh(const float* __restrict__ whh, ushort* __restrict__ wTh) {
    int idx = blockIdx.x * 256 + threadIdx.x;        // over 2*32*1024
    if (idx >= 2 * 32 * 1024) return;
    int j   = idx & 1023;
    int k8  = (idx >> 10) & 31;
    int dir = idx >> 15;
    const float* src = whh + ((long)(dir * 1024 + j)) * 256 + k8 * 8;
    _Float16 o[8];
    #pragma unroll
    for (int i = 0; i < 8; i++) o[i] = (_Float16)src[i];
    *(uint4*)(wTh + (long)idx * 8) = *(uint4*)o;
}

// ---------- plain f16 pack (row-major, n % 8 == 0) ----------
__global__ void pack_f16(const float* __restrict__ in, ushort* __restrict__ out, int n8) {
    int i = blockIdx.x * 256 + threadIdx.x;    // per 8 elements
    if (i >= n8) return;
    float4 a = *(const float4*)(in + (long)i * 8);
    float4 b = *(const float4*)(in + (long)i * 8 + 4);
    _Float16 o[8] = {(_Float16)a.x, (_Float16)a.y, (_Float16)a.z, (_Float16)a.w,
                     (_Float16)b.x, (_Float16)b.y, (_Float16)b.z, (_Float16)b.w};
    *(uint4*)(out + (long)i * 8) = *(uint4*)o;
}

// ---------- f16 xg GEMM: out[m][n] = A[row(m)] . W[n] + bias[n] ----------
// BM=BN=64, BK=16, 256 threads, 4x4 microtile, f16 LDS tiles + fdot2.
// GATHER: A = emb f32 (convert in-flight); else A = H0 f16 (B*S,512).
template <int KDIM, bool GATHER>
__global__ __launch_bounds__(256) void gemm_xg16(
    const void* __restrict__ Av, const int* __restrict__ tokens,
    const ushort* __restrict__ Wh,      // (1024, KDIM) f16 row-major (one dir)
    const float* __restrict__ bias,     // (1024)
    float* __restrict__ out,            // (B*TC, 1024)
    int t_base, int t_sign)
{
    __shared__ uint4 As[2][68];   // [k8][m] : 8 f16 per entry
    __shared__ uint4 Bs[2][68];
    const int tid = threadIdx.x;
    const int m0 = blockIdx.x * 64;
    const int n0 = blockIdx.y * 64;

    const int lr = tid >> 2;            // 0..63 row
    const int lq = tid & 3;             // k-quarter (4 k each)
    const int tcc = (m0 + lr) & (TC - 1);
    const int b   = (m0 + lr) >> TCLOG;
    const int tglob = t_base + t_sign * tcc;
    const long arow = (long)b * SS + tglob;
    const float*  Af = GATHER ? ((const float*)Av + (long)tokens[arow] * KDIM + lq * 4) : nullptr;
    const ushort* Ah = GATHER ? nullptr : ((const ushort*)Av + arow * (long)KDIM + lq * 4);
    const ushort* Wp = Wh + (long)(n0 + lr) * KDIM + lq * 4;

    const int tr = tid >> 4;
    const int tn = tid & 15;

    float acc[4][4];
    #pragma unroll
    for (int i = 0; i < 4; i++)
        #pragma unroll
        for (int j = 0; j < 4; j++) acc[i][j] = 0.f;

    #pragma unroll 1
    for (int k0 = 0; k0 < KDIM; k0 += 16) {
        uint2 aw, bw;
        if (GATHER) {
            float4 av = *(const float4*)(Af + k0);
            aw.x = (uint)f16b(av.x) | ((uint)f16b(av.y) << 16);
            aw.y = (uint)f16b(av.z) | ((uint)f16b(av.w) << 16);
        } else {
            aw = *(const uint2*)(Ah + k0);
        }
        bw = *(const uint2*)(Wp + k0);
        {
            uint2* da = (uint2*)&As[lq >> 1][lr];
            uint2* db = (uint2*)&Bs[lq >> 1][lr];
            da[lq & 1] = aw;
            db[lq & 1] = bw;
        }
        __syncthreads();
        #pragma unroll
        for (int k8 = 0; k8 < 2; k8++) {
            uint4 a[4], w[4];
            #pragma unroll
            for (int i = 0; i < 4; i++) {
                a[i] = As[k8][tr * 4 + i];
                w[i] = Bs[k8][tn * 4 + i];
            }
            #pragma unroll
            for (int i = 0; i < 4; i++)
                #pragma unroll
                for (int j = 0; j < 4; j++)
                    acc[i][j] = dot8h(w[j], a[i], acc[i][j]);
        }
        __syncthreads();
    }

    float4 bc = *(const float4*)(bias + n0 + tn * 4);
    #pragma unroll
    for (int i = 0; i < 4; i++) {
        float4 r;
        r.x = acc[i][0] + bc.x; r.y = acc[i][1] + bc.y;
        r.z = acc[i][2] + bc.z; r.w = acc[i][3] + bc.w;
        *(float4*)(out + (long)(m0 + tr * 4 + i) * G4 + n0 + tn * 4) = r;
    }
}

// ---------- f16-dot2 LSTM scan (round-14, hout -> f16) ----------
__global__ __launch_bounds__(1024, 4) void lstm_hscan(
    const float* __restrict__ xgF, const float* __restrict__ xgB, // [B][TC][1024]
    const ushort* __restrict__ wTh,   // [2][32][1024][8 f16]
    const float* __restrict__ bhh2,   // [2][1024]
    ushort* __restrict__ hout,        // [B*S][512] f16
    float* __restrict__ state,        // [2][B][2][256]
    int tbF, int tbB, int doInit)
{
    const int b = blockIdx.x;
    const int d = blockIdx.y;
    const int j = threadIdx.x;
    const float* xg = (d ? xgB : xgF) + (long)b * TC * G4 + j;
    const uint4* wTd = (const uint4*)(wTh + (long)d * 32 * 1024 * 8);

    __shared__ __align__(16) _Float16 hl[2][256];   // 1 KB double-buffered f16 h
    __shared__ float gl[G4];                        // 4 KB gate exchange
    __shared__ uint4 lwb[KLB * 1024];               // 144 KB f16 weight cache

    #pragma unroll
    for (int k8 = 0; k8 < KLB; k8++)
        lwb[k8 * 1024 + j] = wTd[(long)k8 * 1024 + j];

    const float bj = bhh2[d * G4 + j];
    float c_reg = 0.f, h_reg = 0.f;
    if (j < HH) {
        if (doInit) {
            hl[0][j] = (_Float16)0.f;
        } else {
            h_reg = state[((d * BB + b) * 2 + 0) * HH + j];
            c_reg = state[((d * BB + b) * 2 + 1) * HH + j];
            hl[0][j] = (_Float16)h_reg;
        }
    }
    __syncthreads();

    #pragma unroll 1
    for (int tc = 0; tc < TC; ++tc) {
        const int rb = tc & 1;
        const uint4* hcur = (const uint4*)hl[rb];
        float acc = xg[(long)tc * G4] + bj;

        #pragma unroll
        for (int k8 = 0; k8 < KLB; k8++)
            acc = dot8h(lwb[k8 * 1024 + j], hcur[k8], acc);
        #pragma unroll 6
        for (int k8 = KLB; k8 < 32; k8++)
            acc = dot8h(wTd[(long)k8 * 1024 + j], hcur[k8], acc);

        gl[j] = acc;
        __syncthreads();
        if (j < HH) {
            float gi = gl[j], gf = gl[j + 256], gg = gl[j + 512], go = gl[j + 768];
            c_reg = sigf(gf) * c_reg + sigf(gi) * tanhfast(gg);
            float h = sigf(go) * tanhfast(c_reg);
            h_reg = h;
            _Float16 hh = (_Float16)h;
            hl[rb ^ 1][j] = hh;
            const int t = d ? (tbB - tc) : (tbF + tc);
            hout[((long)(b * SS + t)) * 512 + d * HH + j] = __builtin_bit_cast(ushort, hh);
        }
        __syncthreads();
    }

    if (j < HH) {
        state[((d * BB + b) * 2 + 0) * HH + j] = h_reg;
        state[((d * BB + b) * 2 + 1) * HH + j] = c_reg;
    }
}

// ---------- emissions (f16 h) ----------
__global__ __launch_bounds__(256) void emissions_k16(
    const ushort* __restrict__ h1, const float* __restrict__ clsw,
    const float* __restrict__ clsb, float* __restrict__ em)
{
    long u = (long)blockIdx.x * 256 + threadIdx.x;
    if (u >= (long)BB * SS * NC) return;
    int c = (int)(u % NC);
    long m = u / NC;
    const uint* hr = (const uint*)(h1 + m * 512);      // 256 x (2 f16)
    const float2* wr = (const float2*)(clsw + (long)c * 512);
    float s0 = 0, s1 = 0;
    #pragma unroll 8
    for (int q = 0; q < 256; q += 2) {
        half2v h0 = __builtin_bit_cast(half2v, hr[q]);
        half2v h1v = __builtin_bit_cast(half2v, hr[q + 1]);
        float2 w0 = wr[q], w1 = wr[q + 1];
        s0 += (float)h0.x * w0.x + (float)h0.y * w0.y;
        s1 += (float)h1v.x * w1.x + (float)h1v.y * w1.y;
    }
    em[u] = s0 + s1 + clsb[c];
}

// ---------- CRF log-likelihood per batch row ----------
__global__ __launch_bounds__(64) void crf_llh(
    const float* __restrict__ em, const int* __restrict__ labels,
    const int* __restrict__ mask, const float* __restrict__ start,
    const float* __restrict__ endt, const float* __restrict__ trans,
    float* __restrict__ llh)
{
    int b = blockIdx.x, j = threadIdx.x;
    bool act = j < NC;
    float tcol[NC];
    #pragma unroll
    for (int i = 0; i < NC; i++) tcol[i] = act ? trans[i * NC + j] : 0.f;
    const float* emb_ = em + (long)b * SS * NC;
    const int* lb = labels + b * SS;
    const int* mk = mask + b * SS;
    float alpha = act ? (start[j] + emb_[j]) : -1e30f;

    float num = 0.f;
    int msum = 0;
    for (int t = j; t < SS; t += 64) msum += (mk[t] != 0);
    for (int t = 1 + j; t < SS; t += 64) {
        float m = (float)mk[t];
        num += m * (trans[lb[t - 1] * NC + lb[t]] + emb_[t * NC + lb[t]]);
    }
    for (int o = 32; o > 0; o >>= 1) {
        num  += __shfl_down(num, o);
        msum += __shfl_down(msum, o);
    }
    msum = __shfl(msum, 0);

    for (int t = 1; t < SS; t++) {
        int m = mk[t];
        float emj = act ? emb_[t * NC + j] : 0.f;
        float v[NC];
        float mx = -1e30f;
        #pragma unroll
        for (int i = 0; i < NC; i++) {
            v[i] = __shfl(alpha, i) + tcol[i];
            mx = fmaxf(mx, v[i]);
        }
        float sum = 0.f;
        #pragma unroll
        for (int i = 0; i < NC; i++) sum += __expf(v[i] - mx);
        float nxt = mx + __logf(sum) + emj;
        if (m > 0 && act) alpha = nxt;
    }
    float fin = act ? alpha + endt[j] : -1e30f;
    float mx = -1e30f;
    #pragma unroll
    for (int i = 0; i < NC; i++) mx = fmaxf(mx, __shfl(fin, i));
    float s = 0.f;
    #pragma unroll
    for (int i = 0; i < NC; i++) s += __expf(__shfl(fin, i) - mx);
    float den = mx + __logf(s);
    if (j == 0) {
        int last_idx = msum - 1;
        float numer = num + start[lb[0]] + emb_[lb[0]] + endt[lb[last_idx]];
        llh[b] = numer - den;
    }
}

__global__ __launch_bounds__(64) void loss_k(const float* __restrict__ llh, float* __restrict__ out) {
    int j = threadIdx.x;
    float v = llh[j];
    for (int o = 32; o > 0; o >>= 1) v += __shfl_down(v, o);
    if (j == 0) out[0] = -v / 64.0f;
}

// ---------- Viterbi per batch row ----------
__global__ __launch_bounds__(64) void viterbi_k(
    const float* __restrict__ em, const int* __restrict__ mask,
    const float* __restrict__ start, const float* __restrict__ endt,
    const float* __restrict__ trans, float* __restrict__ outp)
{
    int b = blockIdx.x, j = threadIdx.x;
    bool act = j < NC;
    __shared__ unsigned char bp[SS][NC];
    float tcol[NC];
    #pragma unroll
    for (int i = 0; i < NC; i++) tcol[i] = act ? trans[i * NC + j] : 0.f;
    const float* emb_ = em + (long)b * SS * NC;
    const int* mk = mask + b * SS;
    float score = act ? (start[j] + emb_[j]) : -1e30f;

    for (int t = 1; t < SS; t++) {
        float best = 0.f;
        int bi = 0;
        #pragma unroll
        for (int i = 0; i < NC; i++) {
            float vv = __shfl(score, i) + tcol[i];
            if (i == 0 || vv > best) { best = vv; bi = i; }   // first-max (jnp.argmax)
        }
        int m = mk[t];
        float nxt = best + (act ? emb_[t * NC + j] : 0.f);
        if (act) {
            if (m > 0) { score = nxt; bp[t][j] = (unsigned char)bi; }
            else       { bp[t][j] = (unsigned char)j; }
        }
    }
    float fin = act ? score + endt[j] : -1e30f;
    float bestf = 0.f;
    int last = 0;
    #pragma unroll
    for (int i = 0; i < NC; i++) {
        float vv = __shfl(fin, i);
        if (i == 0 || vv > bestf) { bestf = vv; last = i; }
    }
    __syncthreads();
    if (j == 0) {
        int cur = last;
        outp[1 + (long)b * SS + (SS - 1)] = (float)cur;
        for (int t = SS - 1; t >= 1; t--) {
            cur = bp[t][cur];
            outp[1 + (long)b * SS + (t - 1)] = (float)cur;
        }
    }
}

extern "C" void kernel_launch(void* const* d_in, const int* in_sizes, int n_in,
                              void* d_out, int out_size, void* d_ws, size_t ws_size,
                              hipStream_t stream) {
    const int*   tok    = (const int*)d_in[0];
    const int*   lab    = (const int*)d_in[1];
    const int*   msk    = (const int*)d_in[2];
    const float* emb    = (const float*)d_in[3];
    const float* w_ih0  = (const float*)d_in[4];   // (2,1024,128)
    const float* w_hh0  = (const float*)d_in[5];   // (2,1024,256)
    const float* b_ih0  = (const float*)d_in[6];   // (2,1024)
    const float* b_hh0  = (const float*)d_in[7];
    const float* w_ih1  = (const float*)d_in[8];   // (2,1024,512)
    const float* w_hh1  = (const float*)d_in[9];
    const float* b_ih1  = (const float*)d_in[10];
    const float* b_hh1  = (const float*)d_in[11];
    const float* clsw   = (const float*)d_in[12];  // (9,512)
    const float* clsb   = (const float*)d_in[13];
    const float* startt = (const float*)d_in[14];
    const float* endt   = (const float*)d_in[15];
    const float* transm = (const float*)d_in[16];
    float* out = (float*)d_out;

    // ---- workspace carve (f32 element units); ~154 MB total ----
    size_t nHh  = (size_t)BB * SS * 512 / 2;       // f16 H: 8.39M floats each
    size_t nWT  = (size_t)2 * 32 * 1024 * 8 / 2;   // whh f16: 0.26M floats per layer
    size_t nWI0 = (size_t)2048 * 128 / 2;          // w_ih0 f16
    size_t nWI1 = (size_t)2048 * 512 / 2;          // w_ih1 f16
    size_t nEM  = (size_t)BB * SS * NC;
    size_t nST  = (size_t)2 * BB * 2 * HH;
    size_t nXG  = (size_t)BB * TC * G4;            // 8.39M each dir

    float* H0f  = (float*)d_ws;
    float* H1f  = H0f + nHh;
    float* WT0  = H1f + nHh;
    float* WT1  = WT0 + nWT;
    float* WI0  = WT1 + nWT;
    float* WI1  = WI0 + nWI0;
    float* EM   = WI1 + nWI1;
    float* ST   = EM + nEM;
    float* LLH  = ST + nST;
    float* XGF  = LLH + 64;
    float* XGB  = XGF + nXG;

    ushort* H0h = (ushort*)H0f;
    ushort* H1h = (ushort*)H1f;
    ushort* WH0 = (ushort*)WT0;
    ushort* WH1 = (ushort*)WT1;
    ushort* WI0h = (ushort*)WI0;
    ushort* WI1h = (ushort*)WI1;

    transpose_whhh<<<256, 256, 0, stream>>>(w_hh0, WH0);
    transpose_whhh<<<256, 256, 0, stream>>>(w_hh1, WH1);
    pack_f16<<<(2048 * 128 / 8 + 255) / 256, 256, 0, stream>>>(w_ih0, WI0h, 2048 * 128 / 8);
    pack_f16<<<(2048 * 512 / 8 + 255) / 256, 256, 0, stream>>>(w_ih1, WI1h, 2048 * 512 / 8);

    dim3 gg((BB * TC) / 64, G4 / 64);    // (128, 16)
    dim3 rg(BB, 2);                      // 128 blocks, 1024 threads

    // ---- layer 0 ----
    for (int c = 0; c < NCH; c++) {
        int tbF = c * TC;
        int tbB = SS - 1 - c * TC;
        gemm_xg16<128, true><<<gg, 256, 0, stream>>>(emb, tok, WI0h,              b_ih0,        XGF, tbF, +1);
        gemm_xg16<128, true><<<gg, 256, 0, stream>>>(emb, tok, WI0h + 1024 * 128, b_ih0 + 1024, XGB, tbB, -1);
        lstm_hscan<<<rg, 1024, 0, stream>>>(XGF, XGB, WH0, b_hh0, H0h, ST, tbF, tbB, c == 0);
    }
    // ---- layer 1 ----
    for (int c = 0; c < NCH; c++) {
        int tbF = c * TC;
        int tbB = SS - 1 - c * TC;
        gemm_xg16<512, false><<<gg, 256, 0, stream>>>(H0h, nullptr, WI1h,              b_ih1,        XGF, tbF, +1);
        gemm_xg16<512, false><<<gg, 256, 0, stream>>>(H0h, nullptr, WI1h + 1024 * 512, b_ih1 + 1024, XGB, tbB, -1);
        lstm_hscan<<<rg, 1024, 0, stream>>>(XGF, XGB, WH1, b_hh1, H1h, ST, tbF, tbB, c == 0);
    }

    emissions_k16<<<((BB * SS * NC) + 255) / 256, 256, 0, stream>>>(H1h, clsw, clsb, EM);
    crf_llh<<<BB, 64, 0, stream>>>(EM, lab, msk, startt, endt, transm, LLH);
    loss_k<<<1, 64, 0, stream>>>(LLH, out);
    viterbi_k<<<BB, 64, 0, stream>>>(EM, msk, startt, endt, transm, out);
}

// Round 16
// 2510.957 us; speedup vs baseline: 3.3564x; 1.9524x over previous
//
#include <hip/hip_runtime.h>
#include <math.h>

#define BB 64      // batch
#define SS 512     // seq len
#define EE 128     // embed dim
#define HH 256     // hidden
#define NC 9       // classes
#define G4 1024    // 4*H gates (one direction)
#define TCLOG 7
#define TC 128     // time chunk
#define NCH (SS / TC)

#define KLQ 9      // k16 chunks (of 16 k) cached in LDS = 144 KB (int8)
// streamed: kc in [KLQ, 16) = 7 chunks = 112 KB/step

typedef _Float16 half2v __attribute__((ext_vector_type(2)));

// ---------- activations (overflow-safe, fast) ----------
__device__ __forceinline__ float sigf(float x) {
    return 1.0f / (1.0f + __expf(-x));
}
__device__ __forceinline__ float tanhfast(float x) {
    float a = fabsf(x);
    float e = __expf(-2.0f * a);
    float t = (1.0f - e) / (1.0f + e);
    return copysignf(t, x);
}
// 8 f16 MACs via 4x v_dot2_f32_f16 (f32 accumulate)
__device__ __forceinline__ float dot8h(uint4 w, uint4 h, float acc) {
    acc = __builtin_amdgcn_fdot2(__builtin_bit_cast(half2v, w.x),
                                 __builtin_bit_cast(half2v, h.x), acc, false);
    acc = __builtin_amdgcn_fdot2(__builtin_bit_cast(half2v, w.y),
                                 __builtin_bit_cast(half2v, h.y), acc, false);
    acc = __builtin_amdgcn_fdot2(__builtin_bit_cast(half2v, w.z),
                                 __builtin_bit_cast(half2v, h.z), acc, false);
    acc = __builtin_amdgcn_fdot2(__builtin_bit_cast(half2v, w.w),
                                 __builtin_bit_cast(half2v, h.w), acc, false);
    return acc;
}
// 16 i8 MACs via 4x v_dot4_i32_i8 (exact int32 accumulate)
__device__ __forceinline__ int dot16q(uint4 w, uint4 h, int acc) {
    acc = __builtin_amdgcn_sdot4((int)w.x, (int)h.x, acc, false);
    acc = __builtin_amdgcn_sdot4((int)w.y, (int)h.y, acc, false);
    acc = __builtin_amdgcn_sdot4((int)w.z, (int)h.z, acc, false);
    acc = __builtin_amdgcn_sdot4((int)w.w, (int)h.w, acc, false);
    return acc;
}
__device__ __forceinline__ ushort f16b(float x) {
    return __builtin_bit_cast(ushort, (_Float16)x);
}

// ---------- per-row int8 quantize + transpose: w_hh -> wTq[dir][kc][j][16 i8] ----------
// grid 2048 blocks (row = dir*1024+j), 64 threads (1 wave)
__global__ void quant_whh(const float* __restrict__ whh, uint* __restrict__ wTq,
                          float* __restrict__ swf) {
    const int row = blockIdx.x;        // 0..2047
    const int t = threadIdx.x;         // 0..63, owns k = 4t..4t+3
    float4 v = *(const float4*)(whh + (long)row * 256 + t * 4);
    float mx = fmaxf(fmaxf(fabsf(v.x), fabsf(v.y)), fmaxf(fabsf(v.z), fabsf(v.w)));
    #pragma unroll
    for (int o = 32; o > 0; o >>= 1) mx = fmaxf(mx, __shfl_xor(mx, o));
    float inv = (mx > 0.f) ? 127.f / mx : 0.f;
    int q0 = (int)rintf(v.x * inv) & 255;
    int q1 = (int)rintf(v.y * inv) & 255;
    int q2 = (int)rintf(v.z * inv) & 255;
    int q3 = (int)rintf(v.w * inv) & 255;
    uint u = (uint)q0 | ((uint)q1 << 8) | ((uint)q2 << 16) | ((uint)q3 << 24);
    const int dir = row >> 10, j = row & 1023;
    const int kc = t >> 2, l4 = t & 3;
    wTq[(((long)(dir * 16 + kc) * 1024 + j) << 2) + l4] = u;
    if (t == 0) swf[row] = (mx > 0.f) ? (mx / 127.f) * (1.f / 127.f) : 0.f;  // s_w * s_h
}

// ---------- plain f16 pack (row-major, n % 8 == 0) ----------
__global__ void pack_f16(const float* __restrict__ in, ushort* __restrict__ out, int n8) {
    int i = blockIdx.x * 256 + threadIdx.x;
    if (i >= n8) return;
    float4 a = *(const float4*)(in + (long)i * 8);
    float4 b = *(const float4*)(in + (long)i * 8 + 4);
    _Float16 o[8] = {(_Float16)a.x, (_Float16)a.y, (_Float16)a.z, (_Float16)a.w,
                     (_Float16)b.x, (_Float16)b.y, (_Float16)b.z, (_Float16)b.w};
    *(uint4*)(out + (long)i * 8) = *(uint4*)o;
}

// ---------- f16 xg GEMM (proven round-15) ----------
template <int KDIM, bool GATHER>
__global__ __launch_bounds__(256) void gemm_xg16(
    const void* __restrict__ Av, const int* __restrict__ tokens,
    const ushort* __restrict__ Wh, const float* __restrict__ bias,
    float* __restrict__ out, int t_base, int t_sign)
{
    __shared__ uint4 As[2][68];
    __shared__ uint4 Bs[2][68];
    const int tid = threadIdx.x;
    const int m0 = blockIdx.x * 64;
    const int n0 = blockIdx.y * 64;

    const int lr = tid >> 2;
    const int lq = tid & 3;
    const int tcc = (m0 + lr) & (TC - 1);
    const int b   = (m0 + lr) >> TCLOG;
    const int tglob = t_base + t_sign * tcc;
    const long arow = (long)b * SS + tglob;
    const float*  Af = GATHER ? ((const float*)Av + (long)tokens[arow] * KDIM + lq * 4) : nullptr;
    const ushort* Ah = GATHER ? nullptr : ((const ushort*)Av + arow * (long)KDIM + lq * 4);
    const ushort* Wp = Wh + (long)(n0 + lr) * KDIM + lq * 4;

    const int tr = tid >> 4;
    const int tn = tid & 15;

    float acc[4][4];
    #pragma unroll
    for (int i = 0; i < 4; i++)
        #pragma unroll
        for (int j = 0; j < 4; j++) acc[i][j] = 0.f;

    #pragma unroll 1
    for (int k0 = 0; k0 < KDIM; k0 += 16) {
        uint2 aw, bw;
        if (GATHER) {
            float4 av = *(const float4*)(Af + k0);
            aw.x = (uint)f16b(av.x) | ((uint)f16b(av.y) << 16);
            aw.y = (uint)f16b(av.z) | ((uint)f16b(av.w) << 16);
        } else {
            aw = *(const uint2*)(Ah + k0);
        }
        bw = *(const uint2*)(Wp + k0);
        {
            uint2* da = (uint2*)&As[lq >> 1][lr];
            uint2* db = (uint2*)&Bs[lq >> 1][lr];
            da[lq & 1] = aw;
            db[lq & 1] = bw;
        }
        __syncthreads();
        #pragma unroll
        for (int k8 = 0; k8 < 2; k8++) {
            uint4 a[4], w[4];
            #pragma unroll
            for (int i = 0; i < 4; i++) {
                a[i] = As[k8][tr * 4 + i];
                w[i] = Bs[k8][tn * 4 + i];
            }
            #pragma unroll
            for (int i = 0; i < 4; i++)
                #pragma unroll
                for (int j = 0; j < 4; j++)
                    acc[i][j] = dot8h(w[j], a[i], acc[i][j]);
        }
        __syncthreads();
    }

    float4 bc = *(const float4*)(bias + n0 + tn * 4);
    #pragma unroll
    for (int i = 0; i < 4; i++) {
        float4 r;
        r.x = acc[i][0] + bc.x; r.y = acc[i][1] + bc.y;
        r.z = acc[i][2] + bc.z; r.w = acc[i][3] + bc.w;
        *(float4*)(out + (long)(m0 + tr * 4 + i) * G4 + n0 + tn * 4) = r;
    }
}

// ---------- int8-dot LSTM scan (round-8 structure, sdot4 inner) ----------
// Grid (64 batch, 2 dir), 1024 threads (16 waves = 4/SIMD).
// Thread j owns gate row j: 16 uint4 (16 i8 each).
//   kc [0,KLQ)   -> LDS (144 KB)
//   kc [KLQ,16)  -> streamed from L2 (112 KB/step)
// h quantized to int8 per step (dot input only); c/state/hout stay f32/f16.
__global__ __launch_bounds__(1024, 4) void lstm_qscan(
    const float* __restrict__ xgF, const float* __restrict__ xgB, // [B][TC][1024]
    const uint* __restrict__ wTq,     // [2][16][1024][4 uint]
    const float* __restrict__ swf,    // [2][1024] combined scale s_w*s_h
    const float* __restrict__ bhh2,   // [2][1024]
    ushort* __restrict__ hout,        // [B*S][512] f16
    float* __restrict__ state,        // [2][B][2][256]
    int tbF, int tbB, int doInit)
{
    const int b = blockIdx.x;
    const int d = blockIdx.y;
    const int j = threadIdx.x;
    const float* xg = (d ? xgB : xgF) + (long)b * TC * G4 + j;
    const uint4* wTd = (const uint4*)wTq + (long)d * 16 * 1024;

    __shared__ __align__(16) uint hq[2][64];   // int8 h packed, 256 B each
    __shared__ float gl[G4];                   // 4 KB gate exchange
    __shared__ uint4 lwq[KLQ * 1024];          // 144 KB int8 weight cache

    // ---- LDS weight cache: kc in [0,KLQ) ----
    #pragma unroll
    for (int kc = 0; kc < KLQ; kc++)
        lwq[kc * 1024 + j] = wTd[(long)kc * 1024 + j];

    const float bj  = bhh2[d * G4 + j];
    const float scl = swf[d * G4 + j];
    float c_reg = 0.f, h_reg = 0.f;
    if (j < HH) {
        if (!doInit) {
            h_reg = state[((d * BB + b) * 2 + 0) * HH + j];
            c_reg = state[((d * BB + b) * 2 + 1) * HH + j];
        }
        ((char*)hq[0])[j] = (char)__float2int_rn(h_reg * 127.f);
    }
    __syncthreads();   // covers hq init + lwq fill

    #pragma unroll 1
    for (int tc = 0; tc < TC; ++tc) {
        const int rb = tc & 1;
        const uint4* hc = (const uint4*)hq[rb];   // 16 x uint4 (broadcast)
        int isum = 0;

        // LDS-cached chunks
        #pragma unroll
        for (int kc = 0; kc < KLQ; kc++)
            isum = dot16q(lwq[kc * 1024 + j], hc[kc], isum);
        // L2-streamed chunks
        #pragma unroll
        for (int kc = KLQ; kc < 16; kc++)
            isum = dot16q(wTd[(long)kc * 1024 + j], hc[kc], isum);

        gl[j] = fmaf((float)isum, scl, xg[(long)tc * G4] + bj);
        __syncthreads();
        if (j < HH) {
            float gi = gl[j], gf = gl[j + 256], gg = gl[j + 512], go = gl[j + 768];
            c_reg = sigf(gf) * c_reg + sigf(gi) * tanhfast(gg);
            float h = sigf(go) * tanhfast(c_reg);
            h_reg = h;
            ((char*)hq[rb ^ 1])[j] = (char)__float2int_rn(h * 127.f);
            const int t = d ? (tbB - tc) : (tbF + tc);
            hout[((long)(b * SS + t)) * 512 + d * HH + j] = f16b(h);
        }
        __syncthreads();
    }

    if (j < HH) {
        state[((d * BB + b) * 2 + 0) * HH + j] = h_reg;
        state[((d * BB + b) * 2 + 1) * HH + j] = c_reg;
    }
}

// ---------- emissions (f16 h) ----------
__global__ __launch_bounds__(256) void emissions_k16(
    const ushort* __restrict__ h1, const float* __restrict__ clsw,
    const float* __restrict__ clsb, float* __restrict__ em)
{
    long u = (long)blockIdx.x * 256 + threadIdx.x;
    if (u >= (long)BB * SS * NC) return;
    int c = (int)(u % NC);
    long m = u / NC;
    const uint* hr = (const uint*)(h1 + m * 512);
    const float2* wr = (const float2*)(clsw + (long)c * 512);
    float s0 = 0, s1 = 0;
    #pragma unroll 8
    for (int q = 0; q < 256; q += 2) {
        half2v h0 = __builtin_bit_cast(half2v, hr[q]);
        half2v h1v = __builtin_bit_cast(half2v, hr[q + 1]);
        float2 w0 = wr[q], w1 = wr[q + 1];
        s0 += (float)h0.x * w0.x + (float)h0.y * w0.y;
        s1 += (float)h1v.x * w1.x + (float)h1v.y * w1.y;
    }
    em[u] = s0 + s1 + clsb[c];
}

// ---------- CRF log-likelihood per batch row ----------
__global__ __launch_bounds__(64) void crf_llh(
    const float* __restrict__ em, const int* __restrict__ labels,
    const int* __restrict__ mask, const float* __restrict__ start,
    const float* __restrict__ endt, const float* __restrict__ trans,
    float* __restrict__ llh)
{
    int b = blockIdx.x, j = threadIdx.x;
    bool act = j < NC;
    float tcol[NC];
    #pragma unroll
    for (int i = 0; i < NC; i++) tcol[i] = act ? trans[i * NC + j] : 0.f;
    const float* emb_ = em + (long)b * SS * NC;
    const int* lb = labels + b * SS;
    const int* mk = mask + b * SS;
    float alpha = act ? (start[j] + emb_[j]) : -1e30f;

    float num = 0.f;
    int msum = 0;
    for (int t = j; t < SS; t += 64) msum += (mk[t] != 0);
    for (int t = 1 + j; t < SS; t += 64) {
        float m = (float)mk[t];
        num += m * (trans[lb[t - 1] * NC + lb[t]] + emb_[t * NC + lb[t]]);
    }
    for (int o = 32; o > 0; o >>= 1) {
        num  += __shfl_down(num, o);
        msum += __shfl_down(msum, o);
    }
    msum = __shfl(msum, 0);

    for (int t = 1; t < SS; t++) {
        int m = mk[t];
        float emj = act ? emb_[t * NC + j] : 0.f;
        float v[NC];
        float mx = -1e30f;
        #pragma unroll
        for (int i = 0; i < NC; i++) {
            v[i] = __shfl(alpha, i) + tcol[i];
            mx = fmaxf(mx, v[i]);
        }
        float sum = 0.f;
        #pragma unroll
        for (int i = 0; i < NC; i++) sum += __expf(v[i] - mx);
        float nxt = mx + __logf(sum) + emj;
        if (m > 0 && act) alpha = nxt;
    }
    float fin = act ? alpha + endt[j] : -1e30f;
    float mx = -1e30f;
    #pragma unroll
    for (int i = 0; i < NC; i++) mx = fmaxf(mx, __shfl(fin, i));
    float s = 0.f;
    #pragma unroll
    for (int i = 0; i < NC; i++) s += __expf(__shfl(fin, i) - mx);
    float den = mx + __logf(s);
    if (j == 0) {
        int last_idx = msum - 1;
        float numer = num + start[lb[0]] + emb_[lb[0]] + endt[lb[last_idx]];
        llh[b] = numer - den;
    }
}

__global__ __launch_bounds__(64) void loss_k(const float* __restrict__ llh, float* __restrict__ out) {
    int j = threadIdx.x;
    float v = llh[j];
    for (int o = 32; o > 0; o >>= 1) v += __shfl_down(v, o);
    if (j == 0) out[0] = -v / 64.0f;
}

// ---------- Viterbi per batch row ----------
__global__ __launch_bounds__(64) void viterbi_k(
    const float* __restrict__ em, const int* __restrict__ mask,
    const float* __restrict__ start, const float* __restrict__ endt,
    const float* __restrict__ trans, float* __restrict__ outp)
{
    int b = blockIdx.x, j = threadIdx.x;
    bool act = j < NC;
    __shared__ unsigned char bp[SS][NC];
    float tcol[NC];
    #pragma unroll
    for (int i = 0; i < NC; i++) tcol[i] = act ? trans[i * NC + j] : 0.f;
    const float* emb_ = em + (long)b * SS * NC;
    const int* mk = mask + b * SS;
    float score = act ? (start[j] + emb_[j]) : -1e30f;

    for (int t = 1; t < SS; t++) {
        float best = 0.f;
        int bi = 0;
        #pragma unroll
        for (int i = 0; i < NC; i++) {
            float vv = __shfl(score, i) + tcol[i];
            if (i == 0 || vv > best) { best = vv; bi = i; }   // first-max (jnp.argmax)
        }
        int m = mk[t];
        float nxt = best + (act ? emb_[t * NC + j] : 0.f);
        if (act) {
            if (m > 0) { score = nxt; bp[t][j] = (unsigned char)bi; }
            else       { bp[t][j] = (unsigned char)j; }
        }
    }
    float fin = act ? score + endt[j] : -1e30f;
    float bestf = 0.f;
    int last = 0;
    #pragma unroll
    for (int i = 0; i < NC; i++) {
        float vv = __shfl(fin, i);
        if (i == 0 || vv > bestf) { bestf = vv; last = i; }
    }
    __syncthreads();
    if (j == 0) {
        int cur = last;
        outp[1 + (long)b * SS + (SS - 1)] = (float)cur;
        for (int t = SS - 1; t >= 1; t--) {
            cur = bp[t][cur];
            outp[1 + (long)b * SS + (t - 1)] = (float)cur;
        }
    }
}

extern "C" void kernel_launch(void* const* d_in, const int* in_sizes, int n_in,
                              void* d_out, int out_size, void* d_ws, size_t ws_size,
                              hipStream_t stream) {
    const int*   tok    = (const int*)d_in[0];
    const int*   lab    = (const int*)d_in[1];
    const int*   msk    = (const int*)d_in[2];
    const float* emb    = (const float*)d_in[3];
    const float* w_ih0  = (const float*)d_in[4];   // (2,1024,128)
    const float* w_hh0  = (const float*)d_in[5];   // (2,1024,256)
    const float* b_ih0  = (const float*)d_in[6];   // (2,1024)
    const float* b_hh0  = (const float*)d_in[7];
    const float* w_ih1  = (const float*)d_in[8];   // (2,1024,512)
    const float* w_hh1  = (const float*)d_in[9];
    const float* b_ih1  = (const float*)d_in[10];
    const float* b_hh1  = (const float*)d_in[11];
    const float* clsw   = (const float*)d_in[12];  // (9,512)
    const float* clsb   = (const float*)d_in[13];
    const float* startt = (const float*)d_in[14];
    const float* endt   = (const float*)d_in[15];
    const float* transm = (const float*)d_in[16];
    float* out = (float*)d_out;

    // ---- workspace carve (f32 element units); ~140 MB total ----
    size_t nHh  = (size_t)BB * SS * 512 / 2;       // f16 H: 8.39M units each
    size_t nWQ  = (size_t)2 * 16 * 1024 * 16 / 4;  // whh int8: 0.13M units per layer
    size_t nSW  = (size_t)2 * 1024;                // scales per layer
    size_t nWI0 = (size_t)2048 * 128 / 2;          // w_ih0 f16
    size_t nWI1 = (size_t)2048 * 512 / 2;          // w_ih1 f16
    size_t nEM  = (size_t)BB * SS * NC;
    size_t nST  = (size_t)2 * BB * 2 * HH;
    size_t nXG  = (size_t)BB * TC * G4;            // 8.39M each dir

    float* H0f  = (float*)d_ws;
    float* H1f  = H0f + nHh;
    float* WQ0  = H1f + nHh;
    float* WQ1  = WQ0 + nWQ;
    float* SW0  = WQ1 + nWQ;
    float* SW1  = SW0 + nSW;
    float* WI0  = SW1 + nSW;
    float* WI1  = WI0 + nWI0;
    float* EM   = WI1 + nWI1;
    float* ST   = EM + nEM;
    float* LLH  = ST + nST;
    float* XGF  = LLH + 64;
    float* XGB  = XGF + nXG;

    ushort* H0h = (ushort*)H0f;
    ushort* H1h = (ushort*)H1f;
    ushort* WI0h = (ushort*)WI0;
    ushort* WI1h = (ushort*)WI1;

    quant_whh<<<2048, 64, 0, stream>>>(w_hh0, (uint*)WQ0, SW0);
    quant_whh<<<2048, 64, 0, stream>>>(w_hh1, (uint*)WQ1, SW1);
    pack_f16<<<(2048 * 128 / 8 + 255) / 256, 256, 0, stream>>>(w_ih0, WI0h, 2048 * 128 / 8);
    pack_f16<<<(2048 * 512 / 8 + 255) / 256, 256, 0, stream>>>(w_ih1, WI1h, 2048 * 512 / 8);

    dim3 gg((BB * TC) / 64, G4 / 64);    // (128, 16)
    dim3 rg(BB, 2);                      // 128 blocks, 1024 threads

    // ---- layer 0 ----
    for (int c = 0; c < NCH; c++) {
        int tbF = c * TC;
        int tbB = SS - 1 - c * TC;
        gemm_xg16<128, true><<<gg, 256, 0, stream>>>(emb, tok, WI0h,              b_ih0,        XGF, tbF, +1);
        gemm_xg16<128, true><<<gg, 256, 0, stream>>>(emb, tok, WI0h + 1024 * 128, b_ih0 + 1024, XGB, tbB, -1);
        lstm_qscan<<<rg, 1024, 0, stream>>>(XGF, XGB, (const uint*)WQ0, SW0, b_hh0, H0h, ST, tbF, tbB, c == 0);
    }
    // ---- layer 1 ----
    for (int c = 0; c < NCH; c++) {
        int tbF = c * TC;
        int tbB = SS - 1 - c * TC;
        gemm_xg16<512, false><<<gg, 256, 0, stream>>>(H0h, nullptr, WI1h,              b_ih1,        XGF, tbF, +1);
        gemm_xg16<512, false><<<gg, 256, 0, stream>>>(H0h, nullptr, WI1h + 1024 * 512, b_ih1 + 1024, XGB, tbB, -1);
        lstm_qscan<<<rg, 1024, 0, stream>>>(XGF, XGB, (const uint*)WQ1, SW1, b_hh1, H1h, ST, tbF, tbB, c == 0);
    }

    emissions_k16<<<((BB * SS * NC) + 255) / 256, 256, 0, stream>>>(H1h, clsw, clsb, EM);
    crf_llh<<<BB, 64, 0, stream>>>(EM, lab, msk, startt, endt, transm, LLH);
    loss_k<<<1, 64, 0, stream>>>(LLH, out);
    viterbi_k<<<BB, 64, 0, stream>>>(EM, msk, startt, endt, transm, out);
}